// Round 1
// baseline (1355.000 us; speedup 1.0000x reference)
//
#include <hip/hip_runtime.h>
#include <math.h>

// Problem constants: n=16, C=512, c4=128, qk=16, H=W=32, L=1024.
// All inputs/outputs fp32.
//
// ws layout (float offsets), total 18,031,616 floats = 72.2 MB:
#define OFF_PV   0u          // pv   [16][128][1024]
#define OFF_CAT  2097152u    // cat  [16][384][1024]
#define OFF_Q    8388608u    // q    [2][16][16][1024]  (s=0: sz2, s=1: sz4)
#define OFF_K    8912896u    // k    [2][16][16][1024]
#define OFF_POOL 9437184u    // pool [16][512][20]  ([0:16]=pool4 i4*4+j4, [16:20]=pool2 i2*2+j2)
#define OFF_FEAT 9601024u    // feat [16][128][20]  ([0:4]=feat2, [4:20]=feat4)
#define OFF_Y    9641984u    // y    [16][512][1024]
#define OFF_STAT 18030592u   // stats[512][2] (scale_eff, shift)

// ---------------- pooling: pooled4 (8x8 blocks) + pooled2 derived ----------------
__global__ __launch_bounds__(256) void pool_kernel(const float* __restrict__ x,
                                                   float* __restrict__ pool) {
  int b = blockIdx.x;            // n*512 + c
  int t = threadIdx.x;
  const float4* xp = (const float4*)(x + (size_t)b * 1024);
  float4 v = xp[t];
  float s4 = v.x + v.y + v.z + v.w;
  __shared__ float sm[256];
  __shared__ float p4s[16];
  sm[t] = s4;
  __syncthreads();
  if (t < 16) {                  // t = br*4 + bc
    int br = t >> 2, bc = t & 3;
    float s = 0.f;
#pragma unroll
    for (int rr = 0; rr < 8; ++rr) {
      int base = br * 64 + rr * 8 + bc * 2;
      s += sm[base] + sm[base + 1];
    }
    s *= (1.f / 64.f);
    p4s[t] = s;
    pool[(size_t)b * 20 + t] = s;
  }
  __syncthreads();
  if (t < 4) {                   // t = i2*2 + j2
    int i2 = t >> 1, j2 = t & 1;
    float s = (p4s[(2*i2)*4 + 2*j2]     + p4s[(2*i2)*4 + 2*j2 + 1] +
               p4s[(2*i2+1)*4 + 2*j2]   + p4s[(2*i2+1)*4 + 2*j2 + 1]) * 0.25f;
    pool[(size_t)b * 20 + 16 + t] = s;
  }
}

// ---------------- feat = rce_w[i] @ pooled_i + rce_b[i] (scales sz=2,4) ----------------
__global__ __launch_bounds__(64) void feat_kernel(const float* __restrict__ pool,
                                                  const float* __restrict__ rce_w,
                                                  const float* __restrict__ rce_b,
                                                  float* __restrict__ feat) {
  int o = blockIdx.x, n = blockIdx.y, t = threadIdx.x;
  float part[20];
#pragma unroll
  for (int j = 0; j < 20; ++j) part[j] = 0.f;
  for (int c = t; c < 512; c += 64) {
    const float* pl = pool + ((size_t)n * 512 + c) * 20;
    float w2 = rce_w[(size_t)(128 + o) * 512 + c];   // rce_w[1]
    float w4 = rce_w[(size_t)(256 + o) * 512 + c];   // rce_w[2]
#pragma unroll
    for (int j = 0; j < 4; ++j)  part[j]     += w2 * pl[16 + j];
#pragma unroll
    for (int j = 0; j < 16; ++j) part[4 + j] += w4 * pl[j];
  }
  __shared__ float red[64][20];
#pragma unroll
  for (int j = 0; j < 20; ++j) red[t][j] = part[j];
  __syncthreads();
  if (t < 20) {
    float s = 0.f;
    for (int i = 0; i < 64; ++i) s += red[i][t];
    s += (t < 4) ? rce_b[128 + o] : rce_b[256 + o];
    feat[((size_t)n * 128 + o) * 20 + t] = s;
  }
}

// ------------- q/k fields from basis vectors G=q_w@feat+q_b, H=k_w@feat+k_b -------------
__global__ __launch_bounds__(256) void qk_kernel(const float* __restrict__ feat,
                                                 const float* __restrict__ q_w,
                                                 const float* __restrict__ q_b,
                                                 const float* __restrict__ k_w,
                                                 const float* __restrict__ k_b,
                                                 float* __restrict__ qarr,
                                                 float* __restrict__ karr) {
  int n = blockIdx.x, t = threadIdx.x;
  __shared__ float fL[128 * 20];
  __shared__ float GH[2][16][20];
  for (int idx = t; idx < 2560; idx += 256) fL[idx] = feat[(size_t)n * 2560 + idx];
  __syncthreads();
  for (int idx = t; idx < 640; idx += 256) {
    int which = idx / 320, rem = idx % 320, qc = rem / 20, j = rem % 20;
    const float* w = which ? k_w : q_w;
    float s = which ? k_b[qc] : q_b[qc];
    for (int c = 0; c < 128; ++c) s += w[qc * 128 + c] * fL[c * 20 + j];
    GH[which][qc][j] = s;
  }
  __syncthreads();
  for (int it = 0; it < 256; ++it) {
    int idx = t + 256 * it;   // covers 2*2*16*1024
    int l = idx & 1023, qc = (idx >> 10) & 15, which = (idx >> 14) & 1, s = idx >> 15;
    int row = l >> 5, col = l & 31;
    const float* G = &GH[which][qc][0];
    float val;
    if (s == 0) {
      float a = row * (1.0f / 31.0f), b = col * (1.0f / 31.0f);
      val = (1.f - a) * ((1.f - b) * G[0] + b * G[1]) + a * ((1.f - b) * G[2] + b * G[3]);
    } else {
      float pr = row * (3.0f / 31.0f);
      int lr = (int)pr; if (lr > 2) lr = 2;
      float fr = pr - (float)lr;
      float pc = col * (3.0f / 31.0f);
      int lc = (int)pc; if (lc > 2) lc = 2;
      float fc = pc - (float)lc;
      const float* G4 = G + 4;
      val = (1.f - fr) * ((1.f - fc) * G4[lr*4 + lc]     + fc * G4[lr*4 + lc + 1]) +
            fr         * ((1.f - fc) * G4[(lr+1)*4 + lc] + fc * G4[(lr+1)*4 + lc + 1]);
    }
    float* dst = which ? karr : qarr;
    dst[(((size_t)s * 16 + n) * 16 + qc) * 1024 + l] = val;
  }
}

// ---------------- proj_value: pv[n] = value_w(128x512) @ x[n](512x1024) + b ----------------
__global__ __launch_bounds__(256) void pv_gemm_kernel(const float* __restrict__ x,
                                                      const float* __restrict__ vw,
                                                      const float* __restrict__ vb,
                                                      float* __restrict__ pv) {
  int lt = blockIdx.x, n = blockIdx.y, t = threadIdx.x;
  int l0 = lt * 64;
  int cg = t >> 4, lg = t & 15;
  int c0 = cg * 8, ll0 = lg * 4;
  __shared__ float A[16 * 128];  // [kk][c]
  __shared__ float B[16 * 64];   // [kk][ll]
  float acc[8][4];
#pragma unroll
  for (int i = 0; i < 8; ++i)
#pragma unroll
    for (int j = 0; j < 4; ++j) acc[i][j] = 0.f;

  for (int k0 = 0; k0 < 512; k0 += 16) {
#pragma unroll
    for (int i = 0; i < 8; ++i) {
      int idx = t + 256 * i; int kk = idx >> 7, c = idx & 127;
      A[idx] = vw[(size_t)c * 512 + k0 + kk];
    }
#pragma unroll
    for (int i = 0; i < 4; ++i) {
      int idx = t + 256 * i; int kk = idx >> 6, ll = idx & 63;
      B[idx] = x[((size_t)n * 512 + k0 + kk) * 1024 + l0 + ll];
    }
    __syncthreads();
#pragma unroll
    for (int kk = 0; kk < 16; ++kk) {
      float4 a0 = *(const float4*)&A[kk * 128 + c0];
      float4 a1 = *(const float4*)&A[kk * 128 + c0 + 4];
      float4 b  = *(const float4*)&B[kk * 64 + ll0];
      float av[8] = {a0.x, a0.y, a0.z, a0.w, a1.x, a1.y, a1.z, a1.w};
      float bv[4] = {b.x, b.y, b.z, b.w};
#pragma unroll
      for (int i = 0; i < 8; ++i)
#pragma unroll
        for (int j = 0; j < 4; ++j) acc[i][j] += av[i] * bv[j];
    }
    __syncthreads();
  }
#pragma unroll
  for (int i = 0; i < 8; ++i) {
    float bias = vb[c0 + i];
    float4 o = make_float4(acc[i][0] + bias, acc[i][1] + bias,
                           acc[i][2] + bias, acc[i][3] + bias);
    *(float4*)&pv[((size_t)n * 128 + c0 + i) * 1024 + l0 + ll0] = o;
  }
}

// ------------- scale sz=1 branch: out = broadcast(mean_l pv) into cat[:,0:128,:] -------------
__global__ __launch_bounds__(256) void meanbc_kernel(const float* __restrict__ pv,
                                                     float* __restrict__ cat) {
  int c = blockIdx.x, n = blockIdx.y, t = threadIdx.x;
  const float4* p4 = (const float4*)(pv + ((size_t)n * 128 + c) * 1024);
  float4 v = p4[t];
  float s = v.x + v.y + v.z + v.w;
  for (int o = 32; o > 0; o >>= 1) s += __shfl_down(s, o);
  __shared__ float wsum[4];
  __shared__ float mean_s;
  if ((t & 63) == 0) wsum[t >> 6] = s;
  __syncthreads();
  if (t == 0) mean_s = (wsum[0] + wsum[1] + wsum[2] + wsum[3]) * (1.f / 1024.f);
  __syncthreads();
  float m = mean_s;
  ((float4*)(cat + ((size_t)n * 384 + c) * 1024))[t] = make_float4(m, m, m, m);
}

__device__ __forceinline__ float dot16(const float4 qv[4], const float* kr) {
  const float4* k4 = (const float4*)kr;
  float4 k0 = k4[0], k1 = k4[1], k2 = k4[2], k3 = k4[3];
  return qv[0].x*k0.x + qv[0].y*k0.y + qv[0].z*k0.z + qv[0].w*k0.w
       + qv[1].x*k1.x + qv[1].y*k1.y + qv[1].z*k1.z + qv[1].w*k1.w
       + qv[2].x*k2.x + qv[2].y*k2.y + qv[2].z*k2.z + qv[2].w*k2.w
       + qv[3].x*k3.x + qv[3].y*k3.y + qv[3].z*k3.z + qv[3].w*k3.w;
}

// ------------- flash attention for sz=2 (sc=0) / sz=4 (sc=1): cat[:,128+128*sc,:] -------------
// block: 64 m-rows; thread quad (mi, ci): ci splits l (pass A) / channels (pass B)
__global__ __launch_bounds__(256) void attn_kernel(const float* __restrict__ qarr,
                                                   const float* __restrict__ karr,
                                                   const float* __restrict__ pv,
                                                   float* __restrict__ cat) {
  int mt = blockIdx.x, n = blockIdx.y, sc = blockIdx.z;
  int t = threadIdx.x;
  int mi = t >> 2, ci = t & 3;
  int m = mt * 64 + mi;
  const float* qb  = qarr + (((size_t)sc * 16 + n) * 16) * 1024;
  const float* kb  = karr + (((size_t)sc * 16 + n) * 16) * 1024;
  const float* pvb = pv + (size_t)n * 128 * 1024;

  float4 qv[4];
#pragma unroll
  for (int u = 0; u < 4; ++u) {
    qv[u].x = qb[(size_t)(4*u + 0) * 1024 + m];
    qv[u].y = qb[(size_t)(4*u + 1) * 1024 + m];
    qv[u].z = qb[(size_t)(4*u + 2) * 1024 + m];
    qv[u].w = qb[(size_t)(4*u + 3) * 1024 + m];
  }

  __shared__ float kchT[32 * 20];   // [l][qc], row 20 (16B-aligned rows)
  __shared__ float vch[32 * 144];   // [l][ci*36 + cc] (36-pad per 32-ch group)
  __shared__ float pch[64 * 33];    // [mi][l]

  // ---- pass A: row max + denom (online softmax, each thread does l ≡ ci mod 4) ----
  float mx = -INFINITY, smv = 0.f;
  for (int ch = 0; ch < 32; ++ch) {
    int l0c = ch * 32;
    __syncthreads();
#pragma unroll
    for (int r = 0; r < 2; ++r) {
      int idx = t + 256 * r;
      int qc = idx >> 5, l = idx & 31;
      kchT[l * 20 + qc] = kb[(size_t)qc * 1024 + l0c + l];
    }
    __syncthreads();
#pragma unroll
    for (int j = 0; j < 8; ++j) {
      int l = ci + 4 * j;
      float s = dot16(qv, &kchT[l * 20]);
      float nm = fmaxf(mx, s);
      smv = smv * __expf(mx - nm) + __expf(s - nm);
      mx = nm;
    }
  }
#pragma unroll
  for (int off = 1; off < 4; off <<= 1) {
    float omx = __shfl_xor(mx, off);
    float osm = __shfl_xor(smv, off);
    float nm = fmaxf(mx, omx);
    smv = smv * __expf(mx - nm) + osm * __expf(omx - nm);
    mx = nm;
  }
  float inv = 1.f / smv;

  // ---- pass B: P·V with recomputed probabilities ----
  float4 acc[8];
#pragma unroll
  for (int j = 0; j < 8; ++j) acc[j] = make_float4(0.f, 0.f, 0.f, 0.f);

  for (int ch = 0; ch < 32; ++ch) {
    int l0c = ch * 32;
    __syncthreads();
#pragma unroll
    for (int r = 0; r < 2; ++r) {
      int idx = t + 256 * r;
      int qc = idx >> 5, l = idx & 31;
      kchT[l * 20 + qc] = kb[(size_t)qc * 1024 + l0c + l];
    }
#pragma unroll
    for (int r = 0; r < 16; ++r) {
      int idx = t + 256 * r;
      int c = idx >> 5, l = idx & 31;
      vch[l * 144 + (c >> 5) * 36 + (c & 31)] = pvb[(size_t)c * 1024 + l0c + l];
    }
    __syncthreads();
#pragma unroll
    for (int j = 0; j < 8; ++j) {
      int l = ci * 8 + j;
      float s = dot16(qv, &kchT[l * 20]);
      pch[mi * 33 + l] = __expf(s - mx) * inv;
    }
    __syncthreads();
    for (int l = 0; l < 32; ++l) {
      float p = pch[mi * 33 + l];
      const float4* vr = (const float4*)&vch[l * 144 + ci * 36];
#pragma unroll
      for (int j = 0; j < 8; ++j) {
        float4 v = vr[j];
        acc[j].x += p * v.x; acc[j].y += p * v.y;
        acc[j].z += p * v.z; acc[j].w += p * v.w;
      }
    }
  }
  float* ob = cat + ((size_t)n * 384 + 128 + (size_t)sc * 128) * 1024;
#pragma unroll
  for (int j = 0; j < 8; ++j) {
    int cb = ci * 32 + 4 * j;
    ob[(size_t)(cb + 0) * 1024 + m] = acc[j].x;
    ob[(size_t)(cb + 1) * 1024 + m] = acc[j].y;
    ob[(size_t)(cb + 2) * 1024 + m] = acc[j].z;
    ob[(size_t)(cb + 3) * 1024 + m] = acc[j].w;
  }
}

// ---------------- fusion conv 3x3, 384->512, pad 1 (direct, LDS-tiled) ----------------
// block: 64 oc x 16x16 spatial tile; thread: 8 oc x 8-px strip
__global__ __launch_bounds__(256) void conv_kernel(const float* __restrict__ cat,
                                                   const float* __restrict__ fw,
                                                   float* __restrict__ y) {
  int bx = blockIdx.x;           // sp + n*4  (oc-tile is gridDim.y -> weight L2 locality)
  int sp = bx & 3, n = bx >> 2;
  int oc0 = blockIdx.y * 64;
  int ty0 = (sp >> 1) * 16, tx0 = (sp & 1) * 16;
  int t = threadIdx.x;
  int strip = t & 31, ocg = t >> 5;
  int py = strip >> 1, px0 = (strip & 1) * 8;

  __shared__ float inS[8 * 324];   // 8 ic x 18x18 halo
  __shared__ float wS[64 * 72];    // 64 oc x (8 ic x 9)
  float acc[8][8];
#pragma unroll
  for (int i = 0; i < 8; ++i)
#pragma unroll
    for (int j = 0; j < 8; ++j) acc[i][j] = 0.f;

  for (int ic0 = 0; ic0 < 384; ic0 += 8) {
    __syncthreads();
    for (int r = 0; r < 11; ++r) {
      int idx = t + 256 * r;
      if (idx < 2592) {
        int icc = idx / 324, rem = idx % 324;
        int yy = rem / 18 + ty0 - 1, xx = rem % 18 + tx0 - 1;
        float v = 0.f;
        if (yy >= 0 && yy < 32 && xx >= 0 && xx < 32)
          v = cat[((size_t)n * 384 + ic0 + icc) * 1024 + yy * 32 + xx];
        inS[idx] = v;
      }
    }
#pragma unroll
    for (int r = 0; r < 18; ++r) {
      int idx = t + 256 * r;
      int oc = idx / 72, rem = idx % 72;
      wS[idx] = fw[(size_t)(oc0 + oc) * 3456 + ic0 * 9 + rem];
    }
    __syncthreads();
    for (int icc = 0; icc < 8; ++icc) {
      float iv[3][10];
#pragma unroll
      for (int dy = 0; dy < 3; ++dy)
#pragma unroll
        for (int dx = 0; dx < 10; ++dx)
          iv[dy][dx] = inS[icc * 324 + (py + dy) * 18 + px0 + dx];
#pragma unroll
      for (int ocv = 0; ocv < 8; ++ocv) {
        const float* wp = &wS[(ocg * 8 + ocv) * 72 + icc * 9];
#pragma unroll
        for (int ky = 0; ky < 3; ++ky)
#pragma unroll
          for (int kx = 0; kx < 3; ++kx) {
            float w = wp[ky * 3 + kx];
#pragma unroll
            for (int p = 0; p < 8; ++p)
              acc[ocv][p] += w * iv[ky][p + kx];
          }
      }
    }
  }
#pragma unroll
  for (int ocv = 0; ocv < 8; ++ocv) {
    float* yp = y + ((size_t)n * 512 + oc0 + ocg * 8 + ocv) * 1024
                  + (ty0 + py) * 32 + tx0 + px0;
    *(float4*)yp       = make_float4(acc[ocv][0], acc[ocv][1], acc[ocv][2], acc[ocv][3]);
    *(float4*)(yp + 4) = make_float4(acc[ocv][4], acc[ocv][5], acc[ocv][6], acc[ocv][7]);
  }
}

// ---------------- BN batch stats per channel (training mode, biased var) ----------------
__global__ __launch_bounds__(256) void bnstat_kernel(const float* __restrict__ y,
                                                     const float* __restrict__ bn_scale,
                                                     const float* __restrict__ bn_bias,
                                                     float* __restrict__ stats) {
  int oc = blockIdx.x, t = threadIdx.x;
  float s = 0.f, ss = 0.f;
  for (int n = 0; n < 16; ++n) {
    float4 v = ((const float4*)(y + ((size_t)n * 512 + oc) * 1024))[t];
    s  += v.x + v.y + v.z + v.w;
    ss += v.x * v.x + v.y * v.y + v.z * v.z + v.w * v.w;
  }
  for (int o = 32; o > 0; o >>= 1) {
    s  += __shfl_down(s, o);
    ss += __shfl_down(ss, o);
  }
  __shared__ float rs[4], rss[4];
  if ((t & 63) == 0) { rs[t >> 6] = s; rss[t >> 6] = ss; }
  __syncthreads();
  if (t == 0) {
    float S = rs[0] + rs[1] + rs[2] + rs[3];
    float SS = rss[0] + rss[1] + rss[2] + rss[3];
    float mean = S * (1.f / 16384.f);
    float var = SS * (1.f / 16384.f) - mean * mean;
    float se = bn_scale[oc] / sqrtf(var + 1e-5f);
    stats[oc * 2] = se;
    stats[oc * 2 + 1] = bn_bias[oc] - mean * se;
  }
}

// ---------------- normalize + relu + gamma*y + x ----------------
__global__ __launch_bounds__(256) void final_kernel(const float* __restrict__ y,
                                                    const float* __restrict__ x,
                                                    const float* __restrict__ stats,
                                                    const float* __restrict__ gamma,
                                                    float* __restrict__ outp) {
  int b = blockIdx.x;            // n*512 + c
  int c = b & 511;
  int t = threadIdx.x;
  float se = stats[c * 2], sh = stats[c * 2 + 1], g = gamma[0];
  float4 yv = ((const float4*)(y + (size_t)b * 1024))[t];
  float4 xv = ((const float4*)(x + (size_t)b * 1024))[t];
  float4 o;
  o.x = g * fmaxf(yv.x * se + sh, 0.f) + xv.x;
  o.y = g * fmaxf(yv.y * se + sh, 0.f) + xv.y;
  o.z = g * fmaxf(yv.z * se + sh, 0.f) + xv.z;
  o.w = g * fmaxf(yv.w * se + sh, 0.f) + xv.w;
  ((float4*)(outp + (size_t)b * 1024))[t] = o;
}

extern "C" void kernel_launch(void* const* d_in, const int* in_sizes, int n_in,
                              void* d_out, int out_size, void* d_ws, size_t ws_size,
                              hipStream_t stream) {
  const float* x        = (const float*)d_in[0];
  const float* rce_w    = (const float*)d_in[1];
  const float* rce_b    = (const float*)d_in[2];
  const float* q_w      = (const float*)d_in[3];
  const float* q_b      = (const float*)d_in[4];
  const float* k_w      = (const float*)d_in[5];
  const float* k_b      = (const float*)d_in[6];
  const float* value_w  = (const float*)d_in[7];
  const float* value_b  = (const float*)d_in[8];
  const float* fw       = (const float*)d_in[9];
  const float* bn_scale = (const float*)d_in[10];
  const float* bn_bias  = (const float*)d_in[11];
  const float* gamma    = (const float*)d_in[12];

  float* ws    = (float*)d_ws;
  float* pv    = ws + OFF_PV;
  float* cat   = ws + OFF_CAT;
  float* qarr  = ws + OFF_Q;
  float* karr  = ws + OFF_K;
  float* pool  = ws + OFF_POOL;
  float* feat  = ws + OFF_FEAT;
  float* ybuf  = ws + OFF_Y;
  float* stats = ws + OFF_STAT;
  float* outp  = (float*)d_out;

  hipLaunchKernelGGL(pool_kernel,    dim3(8192),        dim3(256), 0, stream, x, pool);
  hipLaunchKernelGGL(feat_kernel,    dim3(128, 16),     dim3(64),  0, stream, pool, rce_w, rce_b, feat);
  hipLaunchKernelGGL(qk_kernel,      dim3(16),          dim3(256), 0, stream, feat, q_w, q_b, k_w, k_b, qarr, karr);
  hipLaunchKernelGGL(pv_gemm_kernel, dim3(16, 16),      dim3(256), 0, stream, x, value_w, value_b, pv);
  hipLaunchKernelGGL(meanbc_kernel,  dim3(128, 16),     dim3(256), 0, stream, pv, cat);
  hipLaunchKernelGGL(attn_kernel,    dim3(16, 16, 2),   dim3(256), 0, stream, qarr, karr, pv, cat);
  hipLaunchKernelGGL(conv_kernel,    dim3(64, 8),       dim3(256), 0, stream, cat, fw, ybuf);
  hipLaunchKernelGGL(bnstat_kernel,  dim3(512),         dim3(256), 0, stream, ybuf, bn_scale, bn_bias, stats);
  hipLaunchKernelGGL(final_kernel,   dim3(8192),        dim3(256), 0, stream, ybuf, x, stats, gamma, outp);
}

// Round 2
// 841.571 us; speedup vs baseline: 1.6101x; 1.6101x over previous
//
#include <hip/hip_runtime.h>
#include <math.h>

// n=16, C=512, c4=128, qk=16, H=W=32, L=1024. fp32 in/out; conv via bf16 MFMA.
//
// ws layout (float offsets), total 16,178,176 floats = 64.7 MB:
#define OFF_PV    0u          // pv    [16][128][1024] f32
#define OFF_Y     2097152u    // y     [16][512][1024] f32
#define OFF_CATP  10485760u   // catT_p[16][1156][384] bf16 (pixel-major, 34x34 zero-padded)
#define OFF_Q     14036992u   // q     [2][16][16][1024] f32
#define OFF_K     14561280u   // k     [2][16][16][1024] f32
#define OFF_POOL  15085568u   // pool  [16][512][20] f32
#define OFF_FEAT  15249408u   // feat  [16][128][20] f32
#define OFF_AW    15290368u   // Aw    [512][3456] bf16 (k = (ky*3+kx)*384+ic)
#define OFF_MEANS 16175104u   // means [16][128] f32
#define OFF_STAT  16177152u   // stats [512][2] f32

typedef __bf16 bf16x8 __attribute__((ext_vector_type(8)));
typedef float f32x4 __attribute__((ext_vector_type(4)));

__device__ __forceinline__ unsigned short f2bf(float f) {
  unsigned int u = __float_as_uint(f);
  unsigned int r = u + 0x7fff + ((u >> 16) & 1);   // RNE
  return (unsigned short)(r >> 16);
}

__device__ __forceinline__ void gload_lds16(const void* g, void* l) {
  __builtin_amdgcn_global_load_lds(
      (const __attribute__((address_space(1))) unsigned int*)g,
      (__attribute__((address_space(3))) unsigned int*)l, 16, 0, 0);
}

// ---------------- pooling: pooled4 (8x8 blocks) + pooled2 derived ----------------
__global__ __launch_bounds__(256) void pool_kernel(const float* __restrict__ x,
                                                   float* __restrict__ pool) {
  int b = blockIdx.x;            // n*512 + c
  int t = threadIdx.x;
  const float4* xp = (const float4*)(x + (size_t)b * 1024);
  float4 v = xp[t];
  float s4 = v.x + v.y + v.z + v.w;
  __shared__ float sm[256];
  __shared__ float p4s[16];
  sm[t] = s4;
  __syncthreads();
  if (t < 16) {                  // t = br*4 + bc
    int br = t >> 2, bc = t & 3;
    float s = 0.f;
#pragma unroll
    for (int rr = 0; rr < 8; ++rr) {
      int base = br * 64 + rr * 8 + bc * 2;
      s += sm[base] + sm[base + 1];
    }
    s *= (1.f / 64.f);
    p4s[t] = s;
    pool[(size_t)b * 20 + t] = s;
  }
  __syncthreads();
  if (t < 4) {
    int i2 = t >> 1, j2 = t & 1;
    float s = (p4s[(2*i2)*4 + 2*j2]     + p4s[(2*i2)*4 + 2*j2 + 1] +
               p4s[(2*i2+1)*4 + 2*j2]   + p4s[(2*i2+1)*4 + 2*j2 + 1]) * 0.25f;
    pool[(size_t)b * 20 + 16 + t] = s;
  }
}

// ---------------- feat = rce_w[i] @ pooled_i + rce_b[i] (scales sz=2,4) ----------------
__global__ __launch_bounds__(64) void feat_kernel(const float* __restrict__ pool,
                                                  const float* __restrict__ rce_w,
                                                  const float* __restrict__ rce_b,
                                                  float* __restrict__ feat) {
  int o = blockIdx.x, n = blockIdx.y, t = threadIdx.x;
  float part[20];
#pragma unroll
  for (int j = 0; j < 20; ++j) part[j] = 0.f;
  for (int c = t; c < 512; c += 64) {
    const float* pl = pool + ((size_t)n * 512 + c) * 20;
    float w2 = rce_w[(size_t)(128 + o) * 512 + c];
    float w4 = rce_w[(size_t)(256 + o) * 512 + c];
#pragma unroll
    for (int j = 0; j < 4; ++j)  part[j]     += w2 * pl[16 + j];
#pragma unroll
    for (int j = 0; j < 16; ++j) part[4 + j] += w4 * pl[j];
  }
  __shared__ float red[64][20];
#pragma unroll
  for (int j = 0; j < 20; ++j) red[t][j] = part[j];
  __syncthreads();
  if (t < 20) {
    float s = 0.f;
    for (int i = 0; i < 64; ++i) s += red[i][t];
    s += (t < 4) ? rce_b[128 + o] : rce_b[256 + o];
    feat[((size_t)n * 128 + o) * 20 + t] = s;
  }
}

// ------------- q/k fields from basis vectors G=q_w@feat+q_b, H=k_w@feat+k_b -------------
__global__ __launch_bounds__(256) void qk_kernel(const float* __restrict__ feat,
                                                 const float* __restrict__ q_w,
                                                 const float* __restrict__ q_b,
                                                 const float* __restrict__ k_w,
                                                 const float* __restrict__ k_b,
                                                 float* __restrict__ qarr,
                                                 float* __restrict__ karr) {
  int n = blockIdx.x, t = threadIdx.x;
  __shared__ float fL[128 * 20];
  __shared__ float GH[2][16][20];
  for (int idx = t; idx < 2560; idx += 256) fL[idx] = feat[(size_t)n * 2560 + idx];
  __syncthreads();
  for (int idx = t; idx < 640; idx += 256) {
    int which = idx / 320, rem = idx % 320, qc = rem / 20, j = rem % 20;
    const float* w = which ? k_w : q_w;
    float s = which ? k_b[qc] : q_b[qc];
    for (int c = 0; c < 128; ++c) s += w[qc * 128 + c] * fL[c * 20 + j];
    GH[which][qc][j] = s;
  }
  __syncthreads();
  for (int it = 0; it < 256; ++it) {
    int idx = t + 256 * it;
    int l = idx & 1023, qc = (idx >> 10) & 15, which = (idx >> 14) & 1, s = idx >> 15;
    int row = l >> 5, col = l & 31;
    const float* G = &GH[which][qc][0];
    float val;
    if (s == 0) {
      float a = row * (1.0f / 31.0f), b = col * (1.0f / 31.0f);
      val = (1.f - a) * ((1.f - b) * G[0] + b * G[1]) + a * ((1.f - b) * G[2] + b * G[3]);
    } else {
      float pr = row * (3.0f / 31.0f);
      int lr = (int)pr; if (lr > 2) lr = 2;
      float fr = pr - (float)lr;
      float pc = col * (3.0f / 31.0f);
      int lc = (int)pc; if (lc > 2) lc = 2;
      float fc = pc - (float)lc;
      const float* G4 = G + 4;
      val = (1.f - fr) * ((1.f - fc) * G4[lr*4 + lc]     + fc * G4[lr*4 + lc + 1]) +
            fr         * ((1.f - fc) * G4[(lr+1)*4 + lc] + fc * G4[(lr+1)*4 + lc + 1]);
    }
    float* dst = which ? karr : qarr;
    dst[(((size_t)s * 16 + n) * 16 + qc) * 1024 + l] = val;
  }
}

// ---------------- proj_value: pv[n] = value_w(128x512) @ x[n](512x1024) + b ----------------
__global__ __launch_bounds__(256) void pv_gemm_kernel(const float* __restrict__ x,
                                                      const float* __restrict__ vw,
                                                      const float* __restrict__ vb,
                                                      float* __restrict__ pv) {
  int lt = blockIdx.x, n = blockIdx.y, t = threadIdx.x;
  int l0 = lt * 64;
  int cg = t >> 4, lg = t & 15;
  int c0 = cg * 8, ll0 = lg * 4;
  __shared__ float A[16 * 128];
  __shared__ float B[16 * 64];
  float acc[8][4];
#pragma unroll
  for (int i = 0; i < 8; ++i)
#pragma unroll
    for (int j = 0; j < 4; ++j) acc[i][j] = 0.f;

  for (int k0 = 0; k0 < 512; k0 += 16) {
#pragma unroll
    for (int i = 0; i < 8; ++i) {
      int idx = t + 256 * i; int kk = idx >> 7, c = idx & 127;
      A[idx] = vw[(size_t)c * 512 + k0 + kk];
    }
#pragma unroll
    for (int i = 0; i < 4; ++i) {
      int idx = t + 256 * i; int kk = idx >> 6, ll = idx & 63;
      B[idx] = x[((size_t)n * 512 + k0 + kk) * 1024 + l0 + ll];
    }
    __syncthreads();
#pragma unroll
    for (int kk = 0; kk < 16; ++kk) {
      float4 a0 = *(const float4*)&A[kk * 128 + c0];
      float4 a1 = *(const float4*)&A[kk * 128 + c0 + 4];
      float4 b  = *(const float4*)&B[kk * 64 + ll0];
      float av[8] = {a0.x, a0.y, a0.z, a0.w, a1.x, a1.y, a1.z, a1.w};
      float bv[4] = {b.x, b.y, b.z, b.w};
#pragma unroll
      for (int i = 0; i < 8; ++i)
#pragma unroll
        for (int j = 0; j < 4; ++j) acc[i][j] += av[i] * bv[j];
    }
    __syncthreads();
  }
#pragma unroll
  for (int i = 0; i < 8; ++i) {
    float bias = vb[c0 + i];
    float4 o = make_float4(acc[i][0] + bias, acc[i][1] + bias,
                           acc[i][2] + bias, acc[i][3] + bias);
    *(float4*)&pv[((size_t)n * 128 + c0 + i) * 1024 + l0 + ll0] = o;
  }
}

// ---------------- means[n][c] = mean_l pv[n][c][l]  (sz=1 branch is constant) ----------------
__global__ __launch_bounds__(256) void mean_kernel(const float* __restrict__ pv,
                                                   float* __restrict__ means) {
  int c = blockIdx.x, n = blockIdx.y, t = threadIdx.x;
  float4 v = ((const float4*)(pv + ((size_t)n * 128 + c) * 1024))[t];
  float s = v.x + v.y + v.z + v.w;
  for (int o = 32; o > 0; o >>= 1) s += __shfl_down(s, o);
  __shared__ float wsum[4];
  if ((t & 63) == 0) wsum[t >> 6] = s;
  __syncthreads();
  if (t == 0) means[n * 128 + c] = (wsum[0] + wsum[1] + wsum[2] + wsum[3]) * (1.f / 1024.f);
}

// ---- fill catT_p: border rows全zero; interior rows ch0..127 = means (bf16) ----
__global__ __launch_bounds__(128) void fillcat_kernel(const float* __restrict__ means,
                                                      unsigned short* __restrict__ catp) {
  int b = blockIdx.x;            // n*1156 + pp
  int n = b / 1156, pp = b % 1156;
  int py = pp / 34, px = pp % 34;
  int t = threadIdx.x;
  unsigned short* row = catp + (size_t)b * 384;
  if (py == 0 || py == 33 || px == 0 || px == 33) {
    row[t] = 0; row[t + 128] = 0; row[t + 256] = 0;
  } else {
    row[t] = f2bf(means[n * 128 + t]);
  }
}

// ---------------- weight reorder+cast: Aw[oc][(ky*3+kx)*384+ic] = bf16(fw[oc][ic][ky][kx]) ----
__global__ __launch_bounds__(256) void wcast_kernel(const float* __restrict__ fw,
                                                    unsigned short* __restrict__ Aw) {
  int oc = blockIdx.x, t = threadIdx.x;
  for (int j = t; j < 3456; j += 256) {
    int seg = j / 384, ic = j % 384;
    Aw[(size_t)oc * 3456 + j] = f2bf(fw[(size_t)oc * 3456 + ic * 9 + seg]);
  }
}

__device__ __forceinline__ float dot16(const float4 qv[4], const float* kr) {
  const float4* k4 = (const float4*)kr;
  float4 k0 = k4[0], k1 = k4[1], k2 = k4[2], k3 = k4[3];
  return qv[0].x*k0.x + qv[0].y*k0.y + qv[0].z*k0.z + qv[0].w*k0.w
       + qv[1].x*k1.x + qv[1].y*k1.y + qv[1].z*k1.z + qv[1].w*k1.w
       + qv[2].x*k2.x + qv[2].y*k2.y + qv[2].z*k2.z + qv[2].w*k2.w
       + qv[3].x*k3.x + qv[3].y*k3.y + qv[3].z*k3.z + qv[3].w*k3.w;
}

// ------------- flash attention for sz=2 (sc=0) / sz=4 (sc=1) -> catT_p bf16 -------------
__global__ __launch_bounds__(256) void attn_kernel(const float* __restrict__ qarr,
                                                   const float* __restrict__ karr,
                                                   const float* __restrict__ pv,
                                                   unsigned short* __restrict__ catp) {
  int mt = blockIdx.x, n = blockIdx.y, sc = blockIdx.z;
  int t = threadIdx.x;
  int mi = t >> 2, ci = t & 3;
  int m = mt * 64 + mi;
  const float* qb  = qarr + (((size_t)sc * 16 + n) * 16) * 1024;
  const float* kb  = karr + (((size_t)sc * 16 + n) * 16) * 1024;
  const float* pvb = pv + (size_t)n * 128 * 1024;

  float4 qv[4];
#pragma unroll
  for (int u = 0; u < 4; ++u) {
    qv[u].x = qb[(size_t)(4*u + 0) * 1024 + m];
    qv[u].y = qb[(size_t)(4*u + 1) * 1024 + m];
    qv[u].z = qb[(size_t)(4*u + 2) * 1024 + m];
    qv[u].w = qb[(size_t)(4*u + 3) * 1024 + m];
  }

  __shared__ float kchT[32 * 20];
  __shared__ float vch[32 * 144];
  __shared__ float pch[64 * 33];

  // ---- pass A: online-softmax row max + denom ----
  float mx = -INFINITY, smv = 0.f;
  for (int ch = 0; ch < 32; ++ch) {
    int l0c = ch * 32;
    __syncthreads();
#pragma unroll
    for (int r = 0; r < 2; ++r) {
      int idx = t + 256 * r;
      int qc = idx >> 5, l = idx & 31;
      kchT[l * 20 + qc] = kb[(size_t)qc * 1024 + l0c + l];
    }
    __syncthreads();
#pragma unroll
    for (int j = 0; j < 8; ++j) {
      int l = ci + 4 * j;
      float s = dot16(qv, &kchT[l * 20]);
      float nm = fmaxf(mx, s);
      smv = smv * __expf(mx - nm) + __expf(s - nm);
      mx = nm;
    }
  }
#pragma unroll
  for (int off = 1; off < 4; off <<= 1) {
    float omx = __shfl_xor(mx, off);
    float osm = __shfl_xor(smv, off);
    float nm = fmaxf(mx, omx);
    smv = smv * __expf(mx - nm) + osm * __expf(omx - nm);
    mx = nm;
  }
  float inv = 1.f / smv;

  // ---- pass B: P·V ----
  float4 acc[8];
#pragma unroll
  for (int j = 0; j < 8; ++j) acc[j] = make_float4(0.f, 0.f, 0.f, 0.f);

  for (int ch = 0; ch < 32; ++ch) {
    int l0c = ch * 32;
    __syncthreads();
#pragma unroll
    for (int r = 0; r < 2; ++r) {
      int idx = t + 256 * r;
      int qc = idx >> 5, l = idx & 31;
      kchT[l * 20 + qc] = kb[(size_t)qc * 1024 + l0c + l];
    }
#pragma unroll
    for (int r = 0; r < 16; ++r) {
      int idx = t + 256 * r;
      int c = idx >> 5, l = idx & 31;
      vch[l * 144 + (c >> 5) * 36 + (c & 31)] = pvb[(size_t)c * 1024 + l0c + l];
    }
    __syncthreads();
#pragma unroll
    for (int j = 0; j < 8; ++j) {
      int l = ci * 8 + j;
      float s = dot16(qv, &kchT[l * 20]);
      pch[mi * 33 + l] = __expf(s - mx) * inv;
    }
    __syncthreads();
    for (int l = 0; l < 32; ++l) {
      float p = pch[mi * 33 + l];
      const float4* vr = (const float4*)&vch[l * 144 + ci * 36];
#pragma unroll
      for (int j = 0; j < 8; ++j) {
        float4 v = vr[j];
        acc[j].x += p * v.x; acc[j].y += p * v.y;
        acc[j].z += p * v.z; acc[j].w += p * v.w;
      }
    }
  }
  // write bf16 pixel-major: catT_p[n][(y+1)*34 + x+1][128 + sc*128 + ci*32 .. +32]
  unsigned short* ob = catp + ((size_t)n * 1156 + ((m >> 5) + 1) * 34 + (m & 31) + 1) * 384
                     + 128 + sc * 128 + ci * 32;
#pragma unroll
  for (int j = 0; j < 8; ++j) {
    ushort4 o = make_ushort4(f2bf(acc[j].x), f2bf(acc[j].y), f2bf(acc[j].z), f2bf(acc[j].w));
    *(ushort4*)(ob + 4 * j) = o;
  }
}

// ---------------- fusion conv as implicit GEMM (bf16 MFMA, m97 structure) ----------------
// C[M=512][N=16384] = Aw[512][3456] x B^T, B^T rows = shifted catT_p rows.
// block: 256 thr (4 waves 2x2), tile 128x128, BK=32, 16x16x32 bf16 MFMA.
__global__ __launch_bounds__(256) void convmm_kernel(const unsigned short* __restrict__ Aw,
                                                     const unsigned short* __restrict__ catp,
                                                     float* __restrict__ y) {
  int ntile = blockIdx.x;              // 0..127 = n*8 + yt (yt = 4-image-row group)
  int n = ntile >> 3, y0 = (ntile & 7) * 4;
  int m0 = blockIdx.y * 128;
  int t = threadIdx.x;
  int lane = t & 63, wv = t >> 6;
  int wm = (wv & 1) * 64, wn = (wv >> 1) * 64;

  __shared__ short Asm[128 * 32];      // [row m][32 k] bf16, k-quads xor-swizzled
  __shared__ short Bsm[128 * 32];      // [row n(pixel)][32 k]

  // staging address precompute (idx = i*256 + t -> row=idx>>2, q=idx&3, swizzled quad)
  int idx0 = t, idx1 = t + 256;
  int ar0 = idx0 >> 2, aq0 = (idx0 & 3) ^ ((ar0 >> 1) & 3);
  int ar1 = idx1 >> 2, aq1 = (idx1 & 3) ^ ((ar1 >> 1) & 3);
  size_t abase0 = (size_t)(m0 + ar0) * 3456 + aq0 * 8;
  size_t abase1 = (size_t)(m0 + ar1) * 3456 + aq1 * 8;
  size_t bbase0 = ((size_t)n * 1156 + (size_t)(y0 + (ar0 >> 5)) * 34 + (ar0 & 31)) * 384 + aq0 * 8;
  size_t bbase1 = ((size_t)n * 1156 + (size_t)(y0 + (ar1 >> 5)) * 34 + (ar1 & 31)) * 384 + aq1 * 8;
  char* ldsA = (char*)Asm;
  char* ldsB = (char*)Bsm;
  int wvoff = wv * 1024;

  // frag-read addressing (swizzle-consistent): element offs = row*32 + kq*8
  int r15 = lane & 15, kg = lane >> 4;
  int kq = kg ^ ((r15 >> 1) & 3);

  f32x4 acc[4][4];
#pragma unroll
  for (int i = 0; i < 4; ++i)
#pragma unroll
    for (int j = 0; j < 4; ++j) acc[i][j] = (f32x4){0.f, 0.f, 0.f, 0.f};

  for (int seg = 0; seg < 9; ++seg) {
    size_t boffseg = (size_t)((seg / 3) * 34 + (seg % 3)) * 384;
    size_t akkseg = (size_t)seg * 384;
    for (int icc = 0; icc < 12; ++icc) {
      size_t akk = akkseg + icc * 32;
      size_t boff = boffseg + icc * 32;
      __syncthreads();
      gload_lds16(Aw + abase0 + akk,   ldsA + wvoff);
      gload_lds16(Aw + abase1 + akk,   ldsA + 4096 + wvoff);
      gload_lds16(catp + bbase0 + boff, ldsB + wvoff);
      gload_lds16(catp + bbase1 + boff, ldsB + 4096 + wvoff);
      __syncthreads();
      bf16x8 af[4], bf[4];
#pragma unroll
      for (int mt = 0; mt < 4; ++mt)
        af[mt] = *(const bf16x8*)&Asm[(wm + mt * 16 + r15) * 32 + kq * 8];
#pragma unroll
      for (int nt = 0; nt < 4; ++nt)
        bf[nt] = *(const bf16x8*)&Bsm[(wn + nt * 16 + r15) * 32 + kq * 8];
#pragma unroll
      for (int mt = 0; mt < 4; ++mt)
#pragma unroll
        for (int nt = 0; nt < 4; ++nt)
          acc[mt][nt] = __builtin_amdgcn_mfma_f32_16x16x32_bf16(af[mt], bf[nt], acc[mt][nt], 0, 0, 0);
    }
  }

  // epilogue: C col = lane&15 (pixel), row = (lane>>4)*4+reg (oc)
  int pixbase = (ntile & 7) * 128 + wn + (lane & 15);
  int ocbase = m0 + wm + (lane >> 4) * 4;
#pragma unroll
  for (int mt = 0; mt < 4; ++mt)
#pragma unroll
    for (int nt = 0; nt < 4; ++nt) {
      int oc = ocbase + mt * 16;
      int pix = pixbase + nt * 16;
      float* yp = y + ((size_t)n * 512 + oc) * 1024 + pix;
#pragma unroll
      for (int r = 0; r < 4; ++r) yp[(size_t)r * 1024] = acc[mt][nt][r];
    }
}

// ---------------- BN batch stats per channel ----------------
__global__ __launch_bounds__(256) void bnstat_kernel(const float* __restrict__ y,
                                                     const float* __restrict__ bn_scale,
                                                     const float* __restrict__ bn_bias,
                                                     float* __restrict__ stats) {
  int oc = blockIdx.x, t = threadIdx.x;
  float s = 0.f, ss = 0.f;
  for (int n = 0; n < 16; ++n) {
    float4 v = ((const float4*)(y + ((size_t)n * 512 + oc) * 1024))[t];
    s  += v.x + v.y + v.z + v.w;
    ss += v.x * v.x + v.y * v.y + v.z * v.z + v.w * v.w;
  }
  for (int o = 32; o > 0; o >>= 1) {
    s  += __shfl_down(s, o);
    ss += __shfl_down(ss, o);
  }
  __shared__ float rs[4], rss[4];
  if ((t & 63) == 0) { rs[t >> 6] = s; rss[t >> 6] = ss; }
  __syncthreads();
  if (t == 0) {
    float S = rs[0] + rs[1] + rs[2] + rs[3];
    float SS = rss[0] + rss[1] + rss[2] + rss[3];
    float mean = S * (1.f / 16384.f);
    float var = SS * (1.f / 16384.f) - mean * mean;
    float se = bn_scale[oc] / sqrtf(var + 1e-5f);
    stats[oc * 2] = se;
    stats[oc * 2 + 1] = bn_bias[oc] - mean * se;
  }
}

// ---------------- normalize + relu + gamma*y + x ----------------
__global__ __launch_bounds__(256) void final_kernel(const float* __restrict__ y,
                                                    const float* __restrict__ x,
                                                    const float* __restrict__ stats,
                                                    const float* __restrict__ gamma,
                                                    float* __restrict__ outp) {
  int b = blockIdx.x;
  int c = b & 511;
  int t = threadIdx.x;
  float se = stats[c * 2], sh = stats[c * 2 + 1], g = gamma[0];
  float4 yv = ((const float4*)(y + (size_t)b * 1024))[t];
  float4 xv = ((const float4*)(x + (size_t)b * 1024))[t];
  float4 o;
  o.x = g * fmaxf(yv.x * se + sh, 0.f) + xv.x;
  o.y = g * fmaxf(yv.y * se + sh, 0.f) + xv.y;
  o.z = g * fmaxf(yv.z * se + sh, 0.f) + xv.z;
  o.w = g * fmaxf(yv.w * se + sh, 0.f) + xv.w;
  ((float4*)(outp + (size_t)b * 1024))[t] = o;
}

extern "C" void kernel_launch(void* const* d_in, const int* in_sizes, int n_in,
                              void* d_out, int out_size, void* d_ws, size_t ws_size,
                              hipStream_t stream) {
  const float* x        = (const float*)d_in[0];
  const float* rce_w    = (const float*)d_in[1];
  const float* rce_b    = (const float*)d_in[2];
  const float* q_w      = (const float*)d_in[3];
  const float* q_b      = (const float*)d_in[4];
  const float* k_w      = (const float*)d_in[5];
  const float* k_b      = (const float*)d_in[6];
  const float* value_w  = (const float*)d_in[7];
  const float* value_b  = (const float*)d_in[8];
  const float* fw       = (const float*)d_in[9];
  const float* bn_scale = (const float*)d_in[10];
  const float* bn_bias  = (const float*)d_in[11];
  const float* gamma    = (const float*)d_in[12];

  float* ws    = (float*)d_ws;
  float* pv    = ws + OFF_PV;
  float* ybuf  = ws + OFF_Y;
  unsigned short* catp = (unsigned short*)(ws + OFF_CATP);
  float* qarr  = ws + OFF_Q;
  float* karr  = ws + OFF_K;
  float* pool  = ws + OFF_POOL;
  float* feat  = ws + OFF_FEAT;
  unsigned short* Aw = (unsigned short*)(ws + OFF_AW);
  float* means = ws + OFF_MEANS;
  float* stats = ws + OFF_STAT;
  float* outp  = (float*)d_out;

  hipLaunchKernelGGL(pool_kernel,    dim3(8192),      dim3(256), 0, stream, x, pool);
  hipLaunchKernelGGL(feat_kernel,    dim3(128, 16),   dim3(64),  0, stream, pool, rce_w, rce_b, feat);
  hipLaunchKernelGGL(qk_kernel,      dim3(16),        dim3(256), 0, stream, feat, q_w, q_b, k_w, k_b, qarr, karr);
  hipLaunchKernelGGL(pv_gemm_kernel, dim3(16, 16),    dim3(256), 0, stream, x, value_w, value_b, pv);
  hipLaunchKernelGGL(mean_kernel,    dim3(128, 16),   dim3(256), 0, stream, pv, means);
  hipLaunchKernelGGL(fillcat_kernel, dim3(18496),     dim3(128), 0, stream, means, catp);
  hipLaunchKernelGGL(wcast_kernel,   dim3(512),       dim3(256), 0, stream, fw, Aw);
  hipLaunchKernelGGL(attn_kernel,    dim3(16, 16, 2), dim3(256), 0, stream, qarr, karr, pv, catp);
  hipLaunchKernelGGL(convmm_kernel,  dim3(128, 4),    dim3(256), 0, stream, Aw, catp, ybuf);
  hipLaunchKernelGGL(bnstat_kernel,  dim3(512),       dim3(256), 0, stream, ybuf, bn_scale, bn_bias, stats);
  hipLaunchKernelGGL(final_kernel,   dim3(8192),      dim3(256), 0, stream, ybuf, x, stats, gamma, outp);
}

// Round 3
// 436.478 us; speedup vs baseline: 3.1044x; 1.9281x over previous
//
#include <hip/hip_runtime.h>
#include <hip/hip_fp16.h>
#include <math.h>

// n=16, C=512, c4=128, qk=16, H=W=32, L=1024. fp32 in/out.
// conv + attention-PV via MFMA (bf16 / f16).
//
// ws layout (float offsets), total 17,226,752 floats = 68.9 MB:
#define OFF_PV    0u          // pv    [16][128][1024] f32
#define OFF_PVH   2097152u    // pvh   [16][128][1024] f16
#define OFF_Y     3145728u    // y     [16][512][1024] f32  (UNION with P f16 [16][1024][1024])
#define OFF_CATP  11534336u   // catT_p[16][1156][384] bf16 (pixel-major, 34x34 zero-padded)
#define OFF_QT    15085568u   // qT    [2][16][1024][16] f32 (pixel-major rows)
#define OFF_KT    15609856u   // kT    [2][16][1024][16] f32
#define OFF_POOL  16134144u   // pool  [16][512][20] f32
#define OFF_FEAT  16297984u   // feat  [16][128][20] f32
#define OFF_AW    16338944u   // Aw    [512][3456] bf16 (k = (ky*3+kx)*384+ic)
#define OFF_MEANS 17223680u   // means [16][128] f32
#define OFF_STAT  17225728u   // stats [512][2] f32

typedef __bf16 bf16x8 __attribute__((ext_vector_type(8)));
typedef _Float16 f16x8 __attribute__((ext_vector_type(8)));
typedef float f32x4 __attribute__((ext_vector_type(4)));

__device__ __forceinline__ unsigned short f2bf(float f) {
  unsigned int u = __float_as_uint(f);
  unsigned int r = u + 0x7fff + ((u >> 16) & 1);   // RNE
  return (unsigned short)(r >> 16);
}

__device__ __forceinline__ unsigned short f2h(float f) {
  union { _Float16 h; unsigned short u; } cv;
  cv.h = (_Float16)f;
  return cv.u;
}

__device__ __forceinline__ void gload_lds16(const void* g, void* l) {
  __builtin_amdgcn_global_load_lds(
      (const __attribute__((address_space(1))) unsigned int*)g,
      (__attribute__((address_space(3))) unsigned int*)l, 16, 0, 0);
}

// ---------------- pooling: pooled4 (8x8 blocks) + pooled2 derived ----------------
__global__ __launch_bounds__(256) void pool_kernel(const float* __restrict__ x,
                                                   float* __restrict__ pool) {
  int b = blockIdx.x;            // n*512 + c
  int t = threadIdx.x;
  const float4* xp = (const float4*)(x + (size_t)b * 1024);
  float4 v = xp[t];
  float s4 = v.x + v.y + v.z + v.w;
  __shared__ float sm[256];
  __shared__ float p4s[16];
  sm[t] = s4;
  __syncthreads();
  if (t < 16) {
    int br = t >> 2, bc = t & 3;
    float s = 0.f;
#pragma unroll
    for (int rr = 0; rr < 8; ++rr) {
      int base = br * 64 + rr * 8 + bc * 2;
      s += sm[base] + sm[base + 1];
    }
    s *= (1.f / 64.f);
    p4s[t] = s;
    pool[(size_t)b * 20 + t] = s;
  }
  __syncthreads();
  if (t < 4) {
    int i2 = t >> 1, j2 = t & 1;
    float s = (p4s[(2*i2)*4 + 2*j2]     + p4s[(2*i2)*4 + 2*j2 + 1] +
               p4s[(2*i2+1)*4 + 2*j2]   + p4s[(2*i2+1)*4 + 2*j2 + 1]) * 0.25f;
    pool[(size_t)b * 20 + 16 + t] = s;
  }
}

// ---------------- feat = rce_w[i] @ pooled_i + rce_b[i] (scales sz=2,4) ----------------
__global__ __launch_bounds__(64) void feat_kernel(const float* __restrict__ pool,
                                                  const float* __restrict__ rce_w,
                                                  const float* __restrict__ rce_b,
                                                  float* __restrict__ feat) {
  int o = blockIdx.x, n = blockIdx.y, t = threadIdx.x;
  float part[20];
#pragma unroll
  for (int j = 0; j < 20; ++j) part[j] = 0.f;
  for (int c = t; c < 512; c += 64) {
    const float* pl = pool + ((size_t)n * 512 + c) * 20;
    float w2 = rce_w[(size_t)(128 + o) * 512 + c];
    float w4 = rce_w[(size_t)(256 + o) * 512 + c];
#pragma unroll
    for (int j = 0; j < 4; ++j)  part[j]     += w2 * pl[16 + j];
#pragma unroll
    for (int j = 0; j < 16; ++j) part[4 + j] += w4 * pl[j];
  }
  __shared__ float red[64][20];
#pragma unroll
  for (int j = 0; j < 20; ++j) red[t][j] = part[j];
  __syncthreads();
  if (t < 20) {
    float s = 0.f;
    for (int i = 0; i < 64; ++i) s += red[i][t];
    s += (t < 4) ? rce_b[128 + o] : rce_b[256 + o];
    feat[((size_t)n * 128 + o) * 20 + t] = s;
  }
}

// ------------- q/k fields, TRANSPOSED layout [s][n][l][16] for energy kernel -------------
__global__ __launch_bounds__(256) void qk2_kernel(const float* __restrict__ feat,
                                                  const float* __restrict__ q_w,
                                                  const float* __restrict__ q_b,
                                                  const float* __restrict__ k_w,
                                                  const float* __restrict__ k_b,
                                                  float* __restrict__ qT,
                                                  float* __restrict__ kT) {
  int n = blockIdx.x, t = threadIdx.x;
  __shared__ float fL[128 * 20];
  __shared__ float GH[2][16][20];
  for (int idx = t; idx < 2560; idx += 256) fL[idx] = feat[(size_t)n * 2560 + idx];
  __syncthreads();
  for (int idx = t; idx < 640; idx += 256) {
    int which = idx / 320, rem = idx % 320, qc = rem / 20, j = rem % 20;
    const float* w = which ? k_w : q_w;
    float s = which ? k_b[qc] : q_b[qc];
    for (int c = 0; c < 128; ++c) s += w[qc * 128 + c] * fL[c * 20 + j];
    GH[which][qc][j] = s;
  }
  __syncthreads();
  for (int it = 0; it < 16; ++it) {
    int row = t + 256 * it;              // 4096 rows: [s][which][l]
    int l = row & 1023, which = (row >> 10) & 1, s = row >> 11;
    int ry = l >> 5, cx = l & 31;
    int t0, t1, t2, t3;
    float w0, w1, w2, w3;
    if (s == 0) {
      float a = ry * (1.0f / 31.0f), b = cx * (1.0f / 31.0f);
      t0 = 0; t1 = 1; t2 = 2; t3 = 3;
      w0 = (1.f - a) * (1.f - b); w1 = (1.f - a) * b;
      w2 = a * (1.f - b);         w3 = a * b;
    } else {
      float pr = ry * (3.0f / 31.0f);
      int lr = (int)pr; if (lr > 2) lr = 2;
      float fr = pr - (float)lr;
      float pc = cx * (3.0f / 31.0f);
      int lc = (int)pc; if (lc > 2) lc = 2;
      float fc = pc - (float)lc;
      int base = 4 + lr * 4 + lc;
      t0 = base; t1 = base + 1; t2 = base + 4; t3 = base + 5;
      w0 = (1.f - fr) * (1.f - fc); w1 = (1.f - fr) * fc;
      w2 = fr * (1.f - fc);         w3 = fr * fc;
    }
    float val[16];
#pragma unroll
    for (int qc = 0; qc < 16; ++qc) {
      const float* G = GH[which][qc];
      val[qc] = w0 * G[t0] + w1 * G[t1] + w2 * G[t2] + w3 * G[t3];
    }
    float* dst = (which ? kT : qT) + ((size_t)(s * 16 + n) * 1024 + l) * 16;
#pragma unroll
    for (int u = 0; u < 4; ++u)
      *(float4*)(dst + 4 * u) = make_float4(val[4*u], val[4*u+1], val[4*u+2], val[4*u+3]);
  }
}

// ---------------- proj_value: pv[n] = value_w(128x512) @ x[n](512x1024) + b ----------------
// epilogue also writes f16 copy (pvh) for the MFMA PV GEMM.
__global__ __launch_bounds__(256) void pv_gemm_kernel(const float* __restrict__ x,
                                                      const float* __restrict__ vw,
                                                      const float* __restrict__ vb,
                                                      float* __restrict__ pv,
                                                      unsigned short* __restrict__ pvh) {
  int lt = blockIdx.x, n = blockIdx.y, t = threadIdx.x;
  int l0 = lt * 64;
  int cg = t >> 4, lg = t & 15;
  int c0 = cg * 8, ll0 = lg * 4;
  __shared__ float A[16 * 128];
  __shared__ float B[16 * 64];
  float acc[8][4];
#pragma unroll
  for (int i = 0; i < 8; ++i)
#pragma unroll
    for (int j = 0; j < 4; ++j) acc[i][j] = 0.f;

  for (int k0 = 0; k0 < 512; k0 += 16) {
#pragma unroll
    for (int i = 0; i < 8; ++i) {
      int idx = t + 256 * i; int kk = idx >> 7, c = idx & 127;
      A[idx] = vw[(size_t)c * 512 + k0 + kk];
    }
#pragma unroll
    for (int i = 0; i < 4; ++i) {
      int idx = t + 256 * i; int kk = idx >> 6, ll = idx & 63;
      B[idx] = x[((size_t)n * 512 + k0 + kk) * 1024 + l0 + ll];
    }
    __syncthreads();
#pragma unroll
    for (int kk = 0; kk < 16; ++kk) {
      float4 a0 = *(const float4*)&A[kk * 128 + c0];
      float4 a1 = *(const float4*)&A[kk * 128 + c0 + 4];
      float4 b  = *(const float4*)&B[kk * 64 + ll0];
      float av[8] = {a0.x, a0.y, a0.z, a0.w, a1.x, a1.y, a1.z, a1.w};
      float bv[4] = {b.x, b.y, b.z, b.w};
#pragma unroll
      for (int i = 0; i < 8; ++i)
#pragma unroll
        for (int j = 0; j < 4; ++j) acc[i][j] += av[i] * bv[j];
    }
    __syncthreads();
  }
#pragma unroll
  for (int i = 0; i < 8; ++i) {
    float bias = vb[c0 + i];
    float4 o = make_float4(acc[i][0] + bias, acc[i][1] + bias,
                           acc[i][2] + bias, acc[i][3] + bias);
    size_t off = ((size_t)n * 128 + c0 + i) * 1024 + l0 + ll0;
    *(float4*)&pv[off] = o;
    *(ushort4*)&pvh[off] = make_ushort4(f2h(o.x), f2h(o.y), f2h(o.z), f2h(o.w));
  }
}

// ---------------- means[n][c] = mean_l pv[n][c][l]  (sz=1 branch is constant) ----------------
__global__ __launch_bounds__(256) void mean_kernel(const float* __restrict__ pv,
                                                   float* __restrict__ means) {
  int c = blockIdx.x, n = blockIdx.y, t = threadIdx.x;
  float4 v = ((const float4*)(pv + ((size_t)n * 128 + c) * 1024))[t];
  float s = v.x + v.y + v.z + v.w;
  for (int o = 32; o > 0; o >>= 1) s += __shfl_down(s, o);
  __shared__ float wsum[4];
  if ((t & 63) == 0) wsum[t >> 6] = s;
  __syncthreads();
  if (t == 0) means[n * 128 + c] = (wsum[0] + wsum[1] + wsum[2] + wsum[3]) * (1.f / 1024.f);
}

// ---- fill catT_p: border rows all-zero; interior rows ch0..127 = means (bf16) ----
__global__ __launch_bounds__(128) void fillcat_kernel(const float* __restrict__ means,
                                                      unsigned short* __restrict__ catp) {
  int b = blockIdx.x;            // n*1156 + pp
  int n = b / 1156, pp = b % 1156;
  int py = pp / 34, px = pp % 34;
  int t = threadIdx.x;
  unsigned short* row = catp + (size_t)b * 384;
  if (py == 0 || py == 33 || px == 0 || px == 33) {
    row[t] = 0; row[t + 128] = 0; row[t + 256] = 0;
  } else {
    row[t] = f2bf(means[n * 128 + t]);
  }
}

// ---------------- weight reorder+cast ----------------
__global__ __launch_bounds__(256) void wcast_kernel(const float* __restrict__ fw,
                                                    unsigned short* __restrict__ Aw) {
  int oc = blockIdx.x, t = threadIdx.x;
  for (int j = t; j < 3456; j += 256) {
    int seg = j / 384, ic = j % 384;
    Aw[(size_t)oc * 3456 + j] = f2bf(fw[(size_t)oc * 3456 + ic * 9 + seg]);
  }
}

__device__ __forceinline__ float dot16(const float4 qv[4], const float* kr) {
  const float4* k4 = (const float4*)kr;
  float4 k0 = k4[0], k1 = k4[1], k2 = k4[2], k3 = k4[3];
  return qv[0].x*k0.x + qv[0].y*k0.y + qv[0].z*k0.z + qv[0].w*k0.w
       + qv[1].x*k1.x + qv[1].y*k1.y + qv[1].z*k1.z + qv[1].w*k1.w
       + qv[2].x*k2.x + qv[2].y*k2.y + qv[2].z*k2.z + qv[2].w*k2.w
       + qv[3].x*k3.x + qv[3].y*k3.y + qv[3].z*k3.z + qv[3].w*k3.w;
}

// ------------- energy+softmax: P[n][m][l] = softmax_l(q[:,m]·k[:,l]) in f16 -------------
// block: 32 m-rows, thread (mi=t>>3, ci=t&7); l = ci+8j mapping with pitch-20 LDS rows
// -> conflict-free frag reads (all 32 banks exactly once per wave instr).
__global__ __launch_bounds__(256) void energy_kernel(const float* __restrict__ qT,
                                                     const float* __restrict__ kTg,
                                                     unsigned short* __restrict__ P,
                                                     int sc) {
  int mt = blockIdx.x, n = blockIdx.y, t = threadIdx.x;
  int mi = t >> 3, ci = t & 7;
  int m = mt * 32 + mi;
  const float* qrow = qT + (((size_t)sc * 16 + n) * 1024 + m) * 16;
  float4 qv[4];
#pragma unroll
  for (int u = 0; u < 4; ++u) qv[u] = *(const float4*)(qrow + 4 * u);
  const float* kb = kTg + (((size_t)sc * 16 + n) * 1024) * 16;

  __shared__ float kS[128 * 20];   // [l][16], pitch 20
  __shared__ float pb[32 * 132];   // [mi][l] chunk buffer, pitch 132

  // ---- pass A: online max + denom ----
  float mx = -INFINITY, smv = 0.f;
  for (int ch = 0; ch < 8; ++ch) {
    __syncthreads();
#pragma unroll
    for (int r = 0; r < 2; ++r) {
      int idx = t + 256 * r;
      int row = idx >> 2, q4 = idx & 3;
      *(float4*)&kS[row * 20 + q4 * 4] = *(const float4*)&kb[(size_t)(ch * 128 + row) * 16 + q4 * 4];
    }
    __syncthreads();
#pragma unroll
    for (int j = 0; j < 16; ++j) {
      int l = ci + 8 * j;
      float s = dot16(qv, &kS[l * 20]);
      float nm = fmaxf(mx, s);
      smv = smv * __expf(mx - nm) + __expf(s - nm);
      mx = nm;
    }
  }
#pragma unroll
  for (int off = 1; off < 8; off <<= 1) {
    float omx = __shfl_xor(mx, off);
    float osm = __shfl_xor(smv, off);
    float nm = fmaxf(mx, omx);
    smv = smv * __expf(mx - nm) + osm * __expf(omx - nm);
    mx = nm;
  }
  float inv = 1.f / smv;

  // ---- pass B: recompute, normalize, write f16 P (coalesced via LDS chunk) ----
  for (int ch = 0; ch < 8; ++ch) {
    __syncthreads();
#pragma unroll
    for (int r = 0; r < 2; ++r) {
      int idx = t + 256 * r;
      int row = idx >> 2, q4 = idx & 3;
      *(float4*)&kS[row * 20 + q4 * 4] = *(const float4*)&kb[(size_t)(ch * 128 + row) * 16 + q4 * 4];
    }
    __syncthreads();
#pragma unroll
    for (int j = 0; j < 16; ++j) {
      int l = ci + 8 * j;
      float s = dot16(qv, &kS[l * 20]);
      pb[mi * 132 + l] = __expf(s - mx) * inv;
    }
    __syncthreads();
#pragma unroll
    for (int r = 0; r < 4; ++r) {
      int idx = t + 256 * r;
      int row = idx >> 5, l4 = idx & 31;
      float4 v = *(const float4*)&pb[row * 132 + l4 * 4];
      ushort4 o = make_ushort4(f2h(v.x), f2h(v.y), f2h(v.z), f2h(v.w));
      *(ushort4*)&P[((size_t)n * 1024 + mt * 32 + row) * 1024 + ch * 128 + l4 * 4] = o;
    }
  }
}

// ------------- PV GEMM (f16 MFMA): C[c,m] = sum_l pvh[n][c][l] * P[n][m][l] -------------
// tile 128(c) x 64(m), BK=32, grid (16 mtiles, 16 n); writes bf16 into catp.
__global__ __launch_bounds__(256) void pvmm_kernel(const unsigned short* __restrict__ pvh,
                                                   const unsigned short* __restrict__ P,
                                                   unsigned short* __restrict__ catp,
                                                   int sc) {
  int m0 = blockIdx.x * 64;
  int n = blockIdx.y;
  int t = threadIdx.x, lane = t & 63, wv = t >> 6;
  int wm = (wv & 1) * 64, wn = (wv >> 1) * 32;

  __shared__ short Asm[128 * 32];
  __shared__ short Bsm[64 * 32];

  int ar0 = t >> 2,        aq0 = (t & 3) ^ ((ar0 >> 1) & 3);
  int idx1 = t + 256; int ar1 = idx1 >> 2, aq1 = ((idx1 & 3)) ^ ((ar1 >> 1) & 3);
  int br  = t >> 2,        bq  = (t & 3) ^ ((br >> 1) & 3);
  const unsigned short* Ab0 = pvh + ((size_t)n * 128 + ar0) * 1024 + aq0 * 8;
  const unsigned short* Ab1 = pvh + ((size_t)n * 128 + ar1) * 1024 + aq1 * 8;
  const unsigned short* Bb  = P + ((size_t)n * 1024 + m0 + br) * 1024 + bq * 8;
  char* ldsA = (char*)Asm;
  char* ldsB = (char*)Bsm;
  int wvoff = wv * 1024;
  int r15 = lane & 15, kg = lane >> 4;
  int kq = kg ^ ((r15 >> 1) & 3);

  f32x4 acc[4][2];
#pragma unroll
  for (int i = 0; i < 4; ++i)
#pragma unroll
    for (int j = 0; j < 2; ++j) acc[i][j] = (f32x4){0.f, 0.f, 0.f, 0.f};

  for (int k0 = 0; k0 < 1024; k0 += 32) {
    __syncthreads();
    gload_lds16(Ab0 + k0, ldsA + wvoff);
    gload_lds16(Ab1 + k0, ldsA + 4096 + wvoff);
    gload_lds16(Bb + k0,  ldsB + wvoff);
    __syncthreads();
    f16x8 af[4], bfr[2];
#pragma unroll
    for (int mt2 = 0; mt2 < 4; ++mt2)
      af[mt2] = *(const f16x8*)&Asm[(wm + mt2 * 16 + r15) * 32 + kq * 8];
#pragma unroll
    for (int nt2 = 0; nt2 < 2; ++nt2)
      bfr[nt2] = *(const f16x8*)&Bsm[(wn + nt2 * 16 + r15) * 32 + kq * 8];
#pragma unroll
    for (int mt2 = 0; mt2 < 4; ++mt2)
#pragma unroll
      for (int nt2 = 0; nt2 < 2; ++nt2)
        acc[mt2][nt2] = __builtin_amdgcn_mfma_f32_16x16x32_f16(af[mt2], bfr[nt2], acc[mt2][nt2], 0, 0, 0);
  }

  int c_lo = wm + (lane >> 4) * 4;
  int m_lo = wn + (lane & 15);
#pragma unroll
  for (int mt2 = 0; mt2 < 4; ++mt2)
#pragma unroll
    for (int nt2 = 0; nt2 < 2; ++nt2) {
      int pix = m0 + m_lo + nt2 * 16;
      unsigned short* ob = catp + ((size_t)n * 1156 + ((pix >> 5) + 1) * 34 + (pix & 31) + 1) * 384
                         + 128 + sc * 128 + c_lo + mt2 * 16;
#pragma unroll
      for (int r = 0; r < 4; ++r) ob[r] = f2bf(acc[mt2][nt2][r]);
    }
}

// ---------------- fusion conv as implicit GEMM (bf16 MFMA) ----------------
__global__ __launch_bounds__(256) void convmm_kernel(const unsigned short* __restrict__ Aw,
                                                     const unsigned short* __restrict__ catp,
                                                     float* __restrict__ y) {
  int ntile = blockIdx.x;
  int n = ntile >> 3, y0 = (ntile & 7) * 4;
  int m0 = blockIdx.y * 128;
  int t = threadIdx.x;
  int lane = t & 63, wv = t >> 6;
  int wm = (wv & 1) * 64, wn = (wv >> 1) * 64;

  __shared__ short Asm[128 * 32];
  __shared__ short Bsm[128 * 32];

  int idx0 = t, idx1 = t + 256;
  int ar0 = idx0 >> 2, aq0 = (idx0 & 3) ^ ((ar0 >> 1) & 3);
  int ar1 = idx1 >> 2, aq1 = (idx1 & 3) ^ ((ar1 >> 1) & 3);
  size_t abase0 = (size_t)(m0 + ar0) * 3456 + aq0 * 8;
  size_t abase1 = (size_t)(m0 + ar1) * 3456 + aq1 * 8;
  size_t bbase0 = ((size_t)n * 1156 + (size_t)(y0 + (ar0 >> 5)) * 34 + (ar0 & 31)) * 384 + aq0 * 8;
  size_t bbase1 = ((size_t)n * 1156 + (size_t)(y0 + (ar1 >> 5)) * 34 + (ar1 & 31)) * 384 + aq1 * 8;
  char* ldsA = (char*)Asm;
  char* ldsB = (char*)Bsm;
  int wvoff = wv * 1024;

  int r15 = lane & 15, kg = lane >> 4;
  int kq = kg ^ ((r15 >> 1) & 3);

  f32x4 acc[4][4];
#pragma unroll
  for (int i = 0; i < 4; ++i)
#pragma unroll
    for (int j = 0; j < 4; ++j) acc[i][j] = (f32x4){0.f, 0.f, 0.f, 0.f};

  for (int seg = 0; seg < 9; ++seg) {
    size_t boffseg = (size_t)((seg / 3) * 34 + (seg % 3)) * 384;
    size_t akkseg = (size_t)seg * 384;
    for (int icc = 0; icc < 12; ++icc) {
      size_t akk = akkseg + icc * 32;
      size_t boff = boffseg + icc * 32;
      __syncthreads();
      gload_lds16(Aw + abase0 + akk,   ldsA + wvoff);
      gload_lds16(Aw + abase1 + akk,   ldsA + 4096 + wvoff);
      gload_lds16(catp + bbase0 + boff, ldsB + wvoff);
      gload_lds16(catp + bbase1 + boff, ldsB + 4096 + wvoff);
      __syncthreads();
      bf16x8 af[4], bf[4];
#pragma unroll
      for (int mt = 0; mt < 4; ++mt)
        af[mt] = *(const bf16x8*)&Asm[(wm + mt * 16 + r15) * 32 + kq * 8];
#pragma unroll
      for (int nt = 0; nt < 4; ++nt)
        bf[nt] = *(const bf16x8*)&Bsm[(wn + nt * 16 + r15) * 32 + kq * 8];
#pragma unroll
      for (int mt = 0; mt < 4; ++mt)
#pragma unroll
        for (int nt = 0; nt < 4; ++nt)
          acc[mt][nt] = __builtin_amdgcn_mfma_f32_16x16x32_bf16(af[mt], bf[nt], acc[mt][nt], 0, 0, 0);
    }
  }

  int pixbase = (ntile & 7) * 128 + wn + (lane & 15);
  int ocbase = m0 + wm + (lane >> 4) * 4;
#pragma unroll
  for (int mt = 0; mt < 4; ++mt)
#pragma unroll
    for (int nt = 0; nt < 4; ++nt) {
      int oc = ocbase + mt * 16;
      int pix = pixbase + nt * 16;
      float* yp = y + ((size_t)n * 512 + oc) * 1024 + pix;
#pragma unroll
      for (int r = 0; r < 4; ++r) yp[(size_t)r * 1024] = acc[mt][nt][r];
    }
}

// ---------------- BN batch stats per channel ----------------
__global__ __launch_bounds__(256) void bnstat_kernel(const float* __restrict__ y,
                                                     const float* __restrict__ bn_scale,
                                                     const float* __restrict__ bn_bias,
                                                     float* __restrict__ stats) {
  int oc = blockIdx.x, t = threadIdx.x;
  float s = 0.f, ss = 0.f;
  for (int n = 0; n < 16; ++n) {
    float4 v = ((const float4*)(y + ((size_t)n * 512 + oc) * 1024))[t];
    s  += v.x + v.y + v.z + v.w;
    ss += v.x * v.x + v.y * v.y + v.z * v.z + v.w * v.w;
  }
  for (int o = 32; o > 0; o >>= 1) {
    s  += __shfl_down(s, o);
    ss += __shfl_down(ss, o);
  }
  __shared__ float rs[4], rss[4];
  if ((t & 63) == 0) { rs[t >> 6] = s; rss[t >> 6] = ss; }
  __syncthreads();
  if (t == 0) {
    float S = rs[0] + rs[1] + rs[2] + rs[3];
    float SS = rss[0] + rss[1] + rss[2] + rss[3];
    float mean = S * (1.f / 16384.f);
    float var = SS * (1.f / 16384.f) - mean * mean;
    float se = bn_scale[oc] / sqrtf(var + 1e-5f);
    stats[oc * 2] = se;
    stats[oc * 2 + 1] = bn_bias[oc] - mean * se;
  }
}

// ---------------- normalize + relu + gamma*y + x ----------------
__global__ __launch_bounds__(256) void final_kernel(const float* __restrict__ y,
                                                    const float* __restrict__ x,
                                                    const float* __restrict__ stats,
                                                    const float* __restrict__ gamma,
                                                    float* __restrict__ outp) {
  int b = blockIdx.x;
  int c = b & 511;
  int t = threadIdx.x;
  float se = stats[c * 2], sh = stats[c * 2 + 1], g = gamma[0];
  float4 yv = ((const float4*)(y + (size_t)b * 1024))[t];
  float4 xv = ((const float4*)(x + (size_t)b * 1024))[t];
  float4 o;
  o.x = g * fmaxf(yv.x * se + sh, 0.f) + xv.x;
  o.y = g * fmaxf(yv.y * se + sh, 0.f) + xv.y;
  o.z = g * fmaxf(yv.z * se + sh, 0.f) + xv.z;
  o.w = g * fmaxf(yv.w * se + sh, 0.f) + xv.w;
  ((float4*)(outp + (size_t)b * 1024))[t] = o;
}

extern "C" void kernel_launch(void* const* d_in, const int* in_sizes, int n_in,
                              void* d_out, int out_size, void* d_ws, size_t ws_size,
                              hipStream_t stream) {
  const float* x        = (const float*)d_in[0];
  const float* rce_w    = (const float*)d_in[1];
  const float* rce_b    = (const float*)d_in[2];
  const float* q_w      = (const float*)d_in[3];
  const float* q_b      = (const float*)d_in[4];
  const float* k_w      = (const float*)d_in[5];
  const float* k_b      = (const float*)d_in[6];
  const float* value_w  = (const float*)d_in[7];
  const float* value_b  = (const float*)d_in[8];
  const float* fw       = (const float*)d_in[9];
  const float* bn_scale = (const float*)d_in[10];
  const float* bn_bias  = (const float*)d_in[11];
  const float* gamma    = (const float*)d_in[12];

  float* ws    = (float*)d_ws;
  float* pv    = ws + OFF_PV;
  unsigned short* pvh = (unsigned short*)(ws + OFF_PVH);
  float* ybuf  = ws + OFF_Y;
  unsigned short* Pbuf = (unsigned short*)(ws + OFF_Y);   // union: P dead before convmm writes y
  unsigned short* catp = (unsigned short*)(ws + OFF_CATP);
  float* qT    = ws + OFF_QT;
  float* kT    = ws + OFF_KT;
  float* pool  = ws + OFF_POOL;
  float* feat  = ws + OFF_FEAT;
  unsigned short* Aw = (unsigned short*)(ws + OFF_AW);
  float* means = ws + OFF_MEANS;
  float* stats = ws + OFF_STAT;
  float* outp  = (float*)d_out;

  hipLaunchKernelGGL(pool_kernel,    dim3(8192),    dim3(256), 0, stream, x, pool);
  hipLaunchKernelGGL(feat_kernel,    dim3(128, 16), dim3(64),  0, stream, pool, rce_w, rce_b, feat);
  hipLaunchKernelGGL(qk2_kernel,     dim3(16),      dim3(256), 0, stream, feat, q_w, q_b, k_w, k_b, qT, kT);
  hipLaunchKernelGGL(pv_gemm_kernel, dim3(16, 16),  dim3(256), 0, stream, x, value_w, value_b, pv, pvh);
  hipLaunchKernelGGL(mean_kernel,    dim3(128, 16), dim3(256), 0, stream, pv, means);
  hipLaunchKernelGGL(fillcat_kernel, dim3(18496),   dim3(128), 0, stream, means, catp);
  hipLaunchKernelGGL(wcast_kernel,   dim3(512),     dim3(256), 0, stream, fw, Aw);
  hipLaunchKernelGGL(energy_kernel,  dim3(32, 16),  dim3(256), 0, stream, qT, kT, Pbuf, 0);
  hipLaunchKernelGGL(pvmm_kernel,    dim3(16, 16),  dim3(256), 0, stream, pvh, Pbuf, catp, 0);
  hipLaunchKernelGGL(energy_kernel,  dim3(32, 16),  dim3(256), 0, stream, qT, kT, Pbuf, 1);
  hipLaunchKernelGGL(pvmm_kernel,    dim3(16, 16),  dim3(256), 0, stream, pvh, Pbuf, catp, 1);
  hipLaunchKernelGGL(convmm_kernel,  dim3(128, 4),  dim3(256), 0, stream, Aw, catp, ybuf);
  hipLaunchKernelGGL(bnstat_kernel,  dim3(512),     dim3(256), 0, stream, ybuf, bn_scale, bn_bias, stats);
  hipLaunchKernelGGL(final_kernel,   dim3(8192),    dim3(256), 0, stream, ybuf, x, stats, gamma, outp);
}

// Round 4
// 368.825 us; speedup vs baseline: 3.6738x; 1.1834x over previous
//
#include <hip/hip_runtime.h>
#include <hip/hip_fp16.h>
#include <math.h>

// n=16, C=512, c4=128, qk=16, H=W=32, L=1024. fp32 in/out.
// conv + attention-PV + value-proj via MFMA (bf16 / f16).
//
// ws layout (float offsets), total 17,259,520 floats = 69.0 MB:
#define OFF_PV    0u          // pv    [16][128][1024] f32
#define OFF_PVH   2097152u    // pvh   [16][128][1024] f16
#define OFF_Y     3145728u    // y     [16][512][1024] f32
                              //   UNION: xT f16 [16][1024][512] (dead before energy)
                              //   UNION: P  f16 [16][1024][1024] (dead before convmm)
#define OFF_CATP  11534336u   // catT_p[16][1156][384] bf16 (pixel-major, 34x34 zero-padded)
#define OFF_QT    15085568u   // qT    [2][16][1024][16] f32 (pixel-major rows)
#define OFF_KT    15609856u   // kT    [2][16][1024][16] f32
#define OFF_POOL  16134144u   // pool  [16][512][20] f32
#define OFF_FEAT  16297984u   // feat  [16][128][20] f32
#define OFF_AW    16338944u   // Aw    [512][3456] bf16 (k = (ky*3+kx)*384+ic)
#define OFF_MEANS 17223680u   // means [16][128] f32
#define OFF_STAT  17225728u   // stats [512][2] f32
#define OFF_VWH   17226752u   // vwh   [128][512] f16

typedef __bf16 bf16x8 __attribute__((ext_vector_type(8)));
typedef _Float16 f16x8 __attribute__((ext_vector_type(8)));
typedef float f32x4 __attribute__((ext_vector_type(4)));

__device__ __forceinline__ unsigned short f2bf(float f) {
  unsigned int u = __float_as_uint(f);
  unsigned int r = u + 0x7fff + ((u >> 16) & 1);   // RNE
  return (unsigned short)(r >> 16);
}

__device__ __forceinline__ unsigned short f2h(float f) {
  union { _Float16 h; unsigned short u; } cv;
  cv.h = (_Float16)f;
  return cv.u;
}

__device__ __forceinline__ void gload_lds16(const void* g, void* l) {
  __builtin_amdgcn_global_load_lds(
      (const __attribute__((address_space(1))) unsigned int*)g,
      (__attribute__((address_space(3))) unsigned int*)l, 16, 0, 0);
}

// ---------------- pooling: pooled4 (8x8 blocks) + pooled2 derived ----------------
__global__ __launch_bounds__(256) void pool_kernel(const float* __restrict__ x,
                                                   float* __restrict__ pool) {
  int b = blockIdx.x;            // n*512 + c
  int t = threadIdx.x;
  const float4* xp = (const float4*)(x + (size_t)b * 1024);
  float4 v = xp[t];
  float s4 = v.x + v.y + v.z + v.w;
  __shared__ float sm[256];
  __shared__ float p4s[16];
  sm[t] = s4;
  __syncthreads();
  if (t < 16) {
    int br = t >> 2, bc = t & 3;
    float s = 0.f;
#pragma unroll
    for (int rr = 0; rr < 8; ++rr) {
      int base = br * 64 + rr * 8 + bc * 2;
      s += sm[base] + sm[base + 1];
    }
    s *= (1.f / 64.f);
    p4s[t] = s;
    pool[(size_t)b * 20 + t] = s;
  }
  __syncthreads();
  if (t < 4) {
    int i2 = t >> 1, j2 = t & 1;
    float s = (p4s[(2*i2)*4 + 2*j2]     + p4s[(2*i2)*4 + 2*j2 + 1] +
               p4s[(2*i2+1)*4 + 2*j2]   + p4s[(2*i2+1)*4 + 2*j2 + 1]) * 0.25f;
    pool[(size_t)b * 20 + 16 + t] = s;
  }
}

// ---------------- feat = rce_w[i] @ pooled_i + rce_b[i] (scales sz=2,4) ----------------
__global__ __launch_bounds__(64) void feat_kernel(const float* __restrict__ pool,
                                                  const float* __restrict__ rce_w,
                                                  const float* __restrict__ rce_b,
                                                  float* __restrict__ feat) {
  int o = blockIdx.x, n = blockIdx.y, t = threadIdx.x;
  float part[20];
#pragma unroll
  for (int j = 0; j < 20; ++j) part[j] = 0.f;
  for (int c = t; c < 512; c += 64) {
    const float* pl = pool + ((size_t)n * 512 + c) * 20;
    float w2 = rce_w[(size_t)(128 + o) * 512 + c];
    float w4 = rce_w[(size_t)(256 + o) * 512 + c];
#pragma unroll
    for (int j = 0; j < 4; ++j)  part[j]     += w2 * pl[16 + j];
#pragma unroll
    for (int j = 0; j < 16; ++j) part[4 + j] += w4 * pl[j];
  }
  __shared__ float red[64][20];
#pragma unroll
  for (int j = 0; j < 20; ++j) red[t][j] = part[j];
  __syncthreads();
  if (t < 20) {
    float s = 0.f;
    for (int i = 0; i < 64; ++i) s += red[i][t];
    s += (t < 4) ? rce_b[128 + o] : rce_b[256 + o];
    feat[((size_t)n * 128 + o) * 20 + t] = s;
  }
}

// ------------- q/k fields, TRANSPOSED layout [s][n][l][16] for energy kernel -------------
__global__ __launch_bounds__(256) void qk2_kernel(const float* __restrict__ feat,
                                                  const float* __restrict__ q_w,
                                                  const float* __restrict__ q_b,
                                                  const float* __restrict__ k_w,
                                                  const float* __restrict__ k_b,
                                                  float* __restrict__ qT,
                                                  float* __restrict__ kT) {
  int n = blockIdx.x, t = threadIdx.x;
  __shared__ float fL[128 * 20];
  __shared__ float GH[2][16][20];
  for (int idx = t; idx < 2560; idx += 256) fL[idx] = feat[(size_t)n * 2560 + idx];
  __syncthreads();
  for (int idx = t; idx < 640; idx += 256) {
    int which = idx / 320, rem = idx % 320, qc = rem / 20, j = rem % 20;
    const float* w = which ? k_w : q_w;
    float s = which ? k_b[qc] : q_b[qc];
    for (int c = 0; c < 128; ++c) s += w[qc * 128 + c] * fL[c * 20 + j];
    GH[which][qc][j] = s;
  }
  __syncthreads();
  for (int it = 0; it < 16; ++it) {
    int row = t + 256 * it;              // 4096 rows: [s][which][l]
    int l = row & 1023, which = (row >> 10) & 1, s = row >> 11;
    int ry = l >> 5, cx = l & 31;
    int t0, t1, t2, t3;
    float w0, w1, w2, w3;
    if (s == 0) {
      float a = ry * (1.0f / 31.0f), b = cx * (1.0f / 31.0f);
      t0 = 0; t1 = 1; t2 = 2; t3 = 3;
      w0 = (1.f - a) * (1.f - b); w1 = (1.f - a) * b;
      w2 = a * (1.f - b);         w3 = a * b;
    } else {
      float pr = ry * (3.0f / 31.0f);
      int lr = (int)pr; if (lr > 2) lr = 2;
      float fr = pr - (float)lr;
      float pc = cx * (3.0f / 31.0f);
      int lc = (int)pc; if (lc > 2) lc = 2;
      float fc = pc - (float)lc;
      int base = 4 + lr * 4 + lc;
      t0 = base; t1 = base + 1; t2 = base + 4; t3 = base + 5;
      w0 = (1.f - fr) * (1.f - fc); w1 = (1.f - fr) * fc;
      w2 = fr * (1.f - fc);         w3 = fr * fc;
    }
    float val[16];
#pragma unroll
    for (int qc = 0; qc < 16; ++qc) {
      const float* G = GH[which][qc];
      val[qc] = w0 * G[t0] + w1 * G[t1] + w2 * G[t2] + w3 * G[t3];
    }
    float* dst = (which ? kT : qT) + ((size_t)(s * 16 + n) * 1024 + l) * 16;
#pragma unroll
    for (int u = 0; u < 4; ++u)
      *(float4*)(dst + 4 * u) = make_float4(val[4*u], val[4*u+1], val[4*u+2], val[4*u+3]);
  }
}

// ---------------- xT[n][l][c] = f16(x[n][c][l])  (LDS tile transpose) ----------------
__global__ __launch_bounds__(256) void xcast_kernel(const float* __restrict__ x,
                                                    unsigned short* __restrict__ xT) {
  int lt = blockIdx.x, ct = blockIdx.y, n = blockIdx.z;
  int l0 = lt * 64, c0 = ct * 64, t = threadIdx.x;
  __shared__ float tile[64 * 65];
#pragma unroll
  for (int i = 0; i < 16; ++i) {
    int idx = t + 256 * i;
    int c = idx >> 6, l = idx & 63;
    tile[c * 65 + l] = x[((size_t)n * 512 + c0 + c) * 1024 + l0 + l];
  }
  __syncthreads();
#pragma unroll
  for (int i = 0; i < 16; ++i) {
    int idx = t + 256 * i;
    int l = idx >> 6, c = idx & 63;
    xT[((size_t)n * 1024 + l0 + l) * 512 + c0 + c] = f2h(tile[c * 65 + l]);
  }
}

// ---------------- vwh = f16(value_w) ----------------
__global__ __launch_bounds__(256) void vwcast_kernel(const float* __restrict__ vw,
                                                     unsigned short* __restrict__ vwh) {
  int i = blockIdx.x * 256 + threadIdx.x;
  vwh[i] = f2h(vw[i]);
}

// ------------- value-proj GEMM (f16 MFMA): pv[c,l] = sum_k vwh[c,k] xT[n][l][k] + vb -------------
// tile 128(c) x 64(l), BK=32; grid (16 ltiles, 16 n). Writes pv f32 + pvh f16.
__global__ __launch_bounds__(256) void pvmm2_kernel(const unsigned short* __restrict__ vwh,
                                                    const unsigned short* __restrict__ xT,
                                                    const float* __restrict__ vb,
                                                    float* __restrict__ pv,
                                                    unsigned short* __restrict__ pvh) {
  int l0 = blockIdx.x * 64;
  int n = blockIdx.y;
  int t = threadIdx.x, lane = t & 63, wv = t >> 6;
  int wm = (wv & 1) * 64, wn = (wv >> 1) * 32;

  __shared__ short Asm[128 * 32];
  __shared__ short Bsm[64 * 32];

  int ar0 = t >> 2,        aq0 = (t & 3) ^ ((ar0 >> 1) & 3);
  int idx1 = t + 256; int ar1 = idx1 >> 2, aq1 = (idx1 & 3) ^ ((ar1 >> 1) & 3);
  int br  = t >> 2,        bq  = (t & 3) ^ ((br >> 1) & 3);
  const unsigned short* Ab0 = vwh + (size_t)ar0 * 512 + aq0 * 8;
  const unsigned short* Ab1 = vwh + (size_t)ar1 * 512 + aq1 * 8;
  const unsigned short* Bb  = xT + ((size_t)n * 1024 + l0 + br) * 512 + bq * 8;
  char* ldsA = (char*)Asm;
  char* ldsB = (char*)Bsm;
  int wvoff = wv * 1024;
  int r15 = lane & 15, kg = lane >> 4;
  int kq = kg ^ ((r15 >> 1) & 3);

  f32x4 acc[4][2];
#pragma unroll
  for (int i = 0; i < 4; ++i)
#pragma unroll
    for (int j = 0; j < 2; ++j) acc[i][j] = (f32x4){0.f, 0.f, 0.f, 0.f};

  for (int k0 = 0; k0 < 512; k0 += 32) {
    __syncthreads();
    gload_lds16(Ab0 + k0, ldsA + wvoff);
    gload_lds16(Ab1 + k0, ldsA + 4096 + wvoff);
    gload_lds16(Bb + k0,  ldsB + wvoff);
    __syncthreads();
    f16x8 af[4], bfr[2];
#pragma unroll
    for (int mt2 = 0; mt2 < 4; ++mt2)
      af[mt2] = *(const f16x8*)&Asm[(wm + mt2 * 16 + r15) * 32 + kq * 8];
#pragma unroll
    for (int nt2 = 0; nt2 < 2; ++nt2)
      bfr[nt2] = *(const f16x8*)&Bsm[(wn + nt2 * 16 + r15) * 32 + kq * 8];
#pragma unroll
    for (int mt2 = 0; mt2 < 4; ++mt2)
#pragma unroll
      for (int nt2 = 0; nt2 < 2; ++nt2)
        acc[mt2][nt2] = __builtin_amdgcn_mfma_f32_16x16x32_f16(af[mt2], bfr[nt2], acc[mt2][nt2], 0, 0, 0);
  }

  int c_lo = wm + (lane >> 4) * 4;
  int l_lo = wn + (lane & 15);
#pragma unroll
  for (int mt2 = 0; mt2 < 4; ++mt2)
#pragma unroll
    for (int nt2 = 0; nt2 < 2; ++nt2) {
      int l = l0 + l_lo + nt2 * 16;
#pragma unroll
      for (int r = 0; r < 4; ++r) {
        int c = c_lo + mt2 * 16 + r;
        float v = acc[mt2][nt2][r] + vb[c];
        size_t off = ((size_t)n * 128 + c) * 1024 + l;
        pv[off] = v;
        pvh[off] = f2h(v);
      }
    }
}

// ---------------- means[n][c] = mean_l pv[n][c][l]  (sz=1 branch is constant) ----------------
__global__ __launch_bounds__(256) void mean_kernel(const float* __restrict__ pv,
                                                   float* __restrict__ means) {
  int c = blockIdx.x, n = blockIdx.y, t = threadIdx.x;
  float4 v = ((const float4*)(pv + ((size_t)n * 128 + c) * 1024))[t];
  float s = v.x + v.y + v.z + v.w;
  for (int o = 32; o > 0; o >>= 1) s += __shfl_down(s, o);
  __shared__ float wsum[4];
  if ((t & 63) == 0) wsum[t >> 6] = s;
  __syncthreads();
  if (t == 0) means[n * 128 + c] = (wsum[0] + wsum[1] + wsum[2] + wsum[3]) * (1.f / 1024.f);
}

// ---- fill catT_p: border rows all-zero; interior rows ch0..127 = means (bf16) ----
__global__ __launch_bounds__(128) void fillcat_kernel(const float* __restrict__ means,
                                                      unsigned short* __restrict__ catp) {
  int b = blockIdx.x;            // n*1156 + pp
  int n = b / 1156, pp = b % 1156;
  int py = pp / 34, px = pp % 34;
  int t = threadIdx.x;
  unsigned short* row = catp + (size_t)b * 384;
  if (py == 0 || py == 33 || px == 0 || px == 33) {
    row[t] = 0; row[t + 128] = 0; row[t + 256] = 0;
  } else {
    row[t] = f2bf(means[n * 128 + t]);
  }
}

// ---------------- weight reorder+cast ----------------
__global__ __launch_bounds__(256) void wcast_kernel(const float* __restrict__ fw,
                                                    unsigned short* __restrict__ Aw) {
  int oc = blockIdx.x, t = threadIdx.x;
  for (int j = t; j < 3456; j += 256) {
    int seg = j / 384, ic = j % 384;
    Aw[(size_t)oc * 3456 + j] = f2bf(fw[(size_t)oc * 3456 + ic * 9 + seg]);
  }
}

__device__ __forceinline__ float dot16(const float4 qv[4], const float* kr) {
  const float4* k4 = (const float4*)kr;
  float4 k0 = k4[0], k1 = k4[1], k2 = k4[2], k3 = k4[3];
  return qv[0].x*k0.x + qv[0].y*k0.y + qv[0].z*k0.z + qv[0].w*k0.w
       + qv[1].x*k1.x + qv[1].y*k1.y + qv[1].z*k1.z + qv[1].w*k1.w
       + qv[2].x*k2.x + qv[2].y*k2.y + qv[2].z*k2.z + qv[2].w*k2.w
       + qv[3].x*k3.x + qv[3].y*k3.y + qv[3].z*k3.z + qv[3].w*k3.w;
}

// ------------- energy+softmax: P[n][m][l] = softmax_l(q[:,m]·k[:,l]) in f16 -------------
__global__ __launch_bounds__(256) void energy_kernel(const float* __restrict__ qT,
                                                     const float* __restrict__ kTg,
                                                     unsigned short* __restrict__ P,
                                                     int sc) {
  int mt = blockIdx.x, n = blockIdx.y, t = threadIdx.x;
  int mi = t >> 3, ci = t & 7;
  int m = mt * 32 + mi;
  const float* qrow = qT + (((size_t)sc * 16 + n) * 1024 + m) * 16;
  float4 qv[4];
#pragma unroll
  for (int u = 0; u < 4; ++u) qv[u] = *(const float4*)(qrow + 4 * u);
  const float* kb = kTg + (((size_t)sc * 16 + n) * 1024) * 16;

  __shared__ float kS[128 * 20];   // [l][16], pitch 20
  __shared__ float pb[32 * 132];   // [mi][l] chunk buffer, pitch 132

  // ---- pass A: online max + denom ----
  float mx = -INFINITY, smv = 0.f;
  for (int ch = 0; ch < 8; ++ch) {
    __syncthreads();
#pragma unroll
    for (int r = 0; r < 2; ++r) {
      int idx = t + 256 * r;
      int row = idx >> 2, q4 = idx & 3;
      *(float4*)&kS[row * 20 + q4 * 4] = *(const float4*)&kb[(size_t)(ch * 128 + row) * 16 + q4 * 4];
    }
    __syncthreads();
#pragma unroll
    for (int j = 0; j < 16; ++j) {
      int l = ci + 8 * j;
      float s = dot16(qv, &kS[l * 20]);
      float nm = fmaxf(mx, s);
      smv = smv * __expf(mx - nm) + __expf(s - nm);
      mx = nm;
    }
  }
#pragma unroll
  for (int off = 1; off < 8; off <<= 1) {
    float omx = __shfl_xor(mx, off);
    float osm = __shfl_xor(smv, off);
    float nm = fmaxf(mx, omx);
    smv = smv * __expf(mx - nm) + osm * __expf(omx - nm);
    mx = nm;
  }
  float inv = 1.f / smv;

  // ---- pass B: recompute, normalize, write f16 P ----
  for (int ch = 0; ch < 8; ++ch) {
    __syncthreads();
#pragma unroll
    for (int r = 0; r < 2; ++r) {
      int idx = t + 256 * r;
      int row = idx >> 2, q4 = idx & 3;
      *(float4*)&kS[row * 20 + q4 * 4] = *(const float4*)&kb[(size_t)(ch * 128 + row) * 16 + q4 * 4];
    }
    __syncthreads();
#pragma unroll
    for (int j = 0; j < 16; ++j) {
      int l = ci + 8 * j;
      float s = dot16(qv, &kS[l * 20]);
      pb[mi * 132 + l] = __expf(s - mx) * inv;
    }
    __syncthreads();
#pragma unroll
    for (int r = 0; r < 4; ++r) {
      int idx = t + 256 * r;
      int row = idx >> 5, l4 = idx & 31;
      float4 v = *(const float4*)&pb[row * 132 + l4 * 4];
      ushort4 o = make_ushort4(f2h(v.x), f2h(v.y), f2h(v.z), f2h(v.w));
      *(ushort4*)&P[((size_t)n * 1024 + mt * 32 + row) * 1024 + ch * 128 + l4 * 4] = o;
    }
  }
}

// ------------- PV GEMM (f16 MFMA): C[c,m] = sum_l pvh[n][c][l] * P[n][m][l] -------------
__global__ __launch_bounds__(256) void pvmm_kernel(const unsigned short* __restrict__ pvh,
                                                   const unsigned short* __restrict__ P,
                                                   unsigned short* __restrict__ catp,
                                                   int sc) {
  int m0 = blockIdx.x * 64;
  int n = blockIdx.y;
  int t = threadIdx.x, lane = t & 63, wv = t >> 6;
  int wm = (wv & 1) * 64, wn = (wv >> 1) * 32;

  __shared__ short Asm[128 * 32];
  __shared__ short Bsm[64 * 32];

  int ar0 = t >> 2,        aq0 = (t & 3) ^ ((ar0 >> 1) & 3);
  int idx1 = t + 256; int ar1 = idx1 >> 2, aq1 = ((idx1 & 3)) ^ ((ar1 >> 1) & 3);
  int br  = t >> 2,        bq  = (t & 3) ^ ((br >> 1) & 3);
  const unsigned short* Ab0 = pvh + ((size_t)n * 128 + ar0) * 1024 + aq0 * 8;
  const unsigned short* Ab1 = pvh + ((size_t)n * 128 + ar1) * 1024 + aq1 * 8;
  const unsigned short* Bb  = P + ((size_t)n * 1024 + m0 + br) * 1024 + bq * 8;
  char* ldsA = (char*)Asm;
  char* ldsB = (char*)Bsm;
  int wvoff = wv * 1024;
  int r15 = lane & 15, kg = lane >> 4;
  int kq = kg ^ ((r15 >> 1) & 3);

  f32x4 acc[4][2];
#pragma unroll
  for (int i = 0; i < 4; ++i)
#pragma unroll
    for (int j = 0; j < 2; ++j) acc[i][j] = (f32x4){0.f, 0.f, 0.f, 0.f};

  for (int k0 = 0; k0 < 1024; k0 += 32) {
    __syncthreads();
    gload_lds16(Ab0 + k0, ldsA + wvoff);
    gload_lds16(Ab1 + k0, ldsA + 4096 + wvoff);
    gload_lds16(Bb + k0,  ldsB + wvoff);
    __syncthreads();
    f16x8 af[4], bfr[2];
#pragma unroll
    for (int mt2 = 0; mt2 < 4; ++mt2)
      af[mt2] = *(const f16x8*)&Asm[(wm + mt2 * 16 + r15) * 32 + kq * 8];
#pragma unroll
    for (int nt2 = 0; nt2 < 2; ++nt2)
      bfr[nt2] = *(const f16x8*)&Bsm[(wn + nt2 * 16 + r15) * 32 + kq * 8];
#pragma unroll
    for (int mt2 = 0; mt2 < 4; ++mt2)
#pragma unroll
      for (int nt2 = 0; nt2 < 2; ++nt2)
        acc[mt2][nt2] = __builtin_amdgcn_mfma_f32_16x16x32_f16(af[mt2], bfr[nt2], acc[mt2][nt2], 0, 0, 0);
  }

  int c_lo = wm + (lane >> 4) * 4;
  int m_lo = wn + (lane & 15);
#pragma unroll
  for (int mt2 = 0; mt2 < 4; ++mt2)
#pragma unroll
    for (int nt2 = 0; nt2 < 2; ++nt2) {
      int pix = m0 + m_lo + nt2 * 16;
      unsigned short* ob = catp + ((size_t)n * 1156 + ((pix >> 5) + 1) * 34 + (pix & 31) + 1) * 384
                         + 128 + sc * 128 + c_lo + mt2 * 16;
#pragma unroll
      for (int r = 0; r < 4; ++r) ob[r] = f2bf(acc[mt2][nt2][r]);
    }
}

// ---------------- fusion conv as implicit GEMM (bf16 MFMA) ----------------
__global__ __launch_bounds__(256) void convmm_kernel(const unsigned short* __restrict__ Aw,
                                                     const unsigned short* __restrict__ catp,
                                                     float* __restrict__ y) {
  int ntile = blockIdx.x;
  int n = ntile >> 3, y0 = (ntile & 7) * 4;
  int m0 = blockIdx.y * 128;
  int t = threadIdx.x;
  int lane = t & 63, wv = t >> 6;
  int wm = (wv & 1) * 64, wn = (wv >> 1) * 64;

  __shared__ short Asm[128 * 32];
  __shared__ short Bsm[128 * 32];

  int idx0 = t, idx1 = t + 256;
  int ar0 = idx0 >> 2, aq0 = (idx0 & 3) ^ ((ar0 >> 1) & 3);
  int ar1 = idx1 >> 2, aq1 = (idx1 & 3) ^ ((ar1 >> 1) & 3);
  size_t abase0 = (size_t)(m0 + ar0) * 3456 + aq0 * 8;
  size_t abase1 = (size_t)(m0 + ar1) * 3456 + aq1 * 8;
  size_t bbase0 = ((size_t)n * 1156 + (size_t)(y0 + (ar0 >> 5)) * 34 + (ar0 & 31)) * 384 + aq0 * 8;
  size_t bbase1 = ((size_t)n * 1156 + (size_t)(y0 + (ar1 >> 5)) * 34 + (ar1 & 31)) * 384 + aq1 * 8;
  char* ldsA = (char*)Asm;
  char* ldsB = (char*)Bsm;
  int wvoff = wv * 1024;

  int r15 = lane & 15, kg = lane >> 4;
  int kq = kg ^ ((r15 >> 1) & 3);

  f32x4 acc[4][4];
#pragma unroll
  for (int i = 0; i < 4; ++i)
#pragma unroll
    for (int j = 0; j < 4; ++j) acc[i][j] = (f32x4){0.f, 0.f, 0.f, 0.f};

  for (int seg = 0; seg < 9; ++seg) {
    size_t boffseg = (size_t)((seg / 3) * 34 + (seg % 3)) * 384;
    size_t akkseg = (size_t)seg * 384;
    for (int icc = 0; icc < 12; ++icc) {
      size_t akk = akkseg + icc * 32;
      size_t boff = boffseg + icc * 32;
      __syncthreads();
      gload_lds16(Aw + abase0 + akk,   ldsA + wvoff);
      gload_lds16(Aw + abase1 + akk,   ldsA + 4096 + wvoff);
      gload_lds16(catp + bbase0 + boff, ldsB + wvoff);
      gload_lds16(catp + bbase1 + boff, ldsB + 4096 + wvoff);
      __syncthreads();
      bf16x8 af[4], bf[4];
#pragma unroll
      for (int mt = 0; mt < 4; ++mt)
        af[mt] = *(const bf16x8*)&Asm[(wm + mt * 16 + r15) * 32 + kq * 8];
#pragma unroll
      for (int nt = 0; nt < 4; ++nt)
        bf[nt] = *(const bf16x8*)&Bsm[(wn + nt * 16 + r15) * 32 + kq * 8];
#pragma unroll
      for (int mt = 0; mt < 4; ++mt)
#pragma unroll
        for (int nt = 0; nt < 4; ++nt)
          acc[mt][nt] = __builtin_amdgcn_mfma_f32_16x16x32_bf16(af[mt], bf[nt], acc[mt][nt], 0, 0, 0);
    }
  }

  int pixbase = (ntile & 7) * 128 + wn + (lane & 15);
  int ocbase = m0 + wm + (lane >> 4) * 4;
#pragma unroll
  for (int mt = 0; mt < 4; ++mt)
#pragma unroll
    for (int nt = 0; nt < 4; ++nt) {
      int oc = ocbase + mt * 16;
      int pix = pixbase + nt * 16;
      float* yp = y + ((size_t)n * 512 + oc) * 1024 + pix;
#pragma unroll
      for (int r = 0; r < 4; ++r) yp[(size_t)r * 1024] = acc[mt][nt][r];
    }
}

// ---------------- BN batch stats per channel ----------------
__global__ __launch_bounds__(256) void bnstat_kernel(const float* __restrict__ y,
                                                     const float* __restrict__ bn_scale,
                                                     const float* __restrict__ bn_bias,
                                                     float* __restrict__ stats) {
  int oc = blockIdx.x, t = threadIdx.x;
  float s = 0.f, ss = 0.f;
  for (int n = 0; n < 16; ++n) {
    float4 v = ((const float4*)(y + ((size_t)n * 512 + oc) * 1024))[t];
    s  += v.x + v.y + v.z + v.w;
    ss += v.x * v.x + v.y * v.y + v.z * v.z + v.w * v.w;
  }
  for (int o = 32; o > 0; o >>= 1) {
    s  += __shfl_down(s, o);
    ss += __shfl_down(ss, o);
  }
  __shared__ float rs[4], rss[4];
  if ((t & 63) == 0) { rs[t >> 6] = s; rss[t >> 6] = ss; }
  __syncthreads();
  if (t == 0) {
    float S = rs[0] + rs[1] + rs[2] + rs[3];
    float SS = rss[0] + rss[1] + rss[2] + rss[3];
    float mean = S * (1.f / 16384.f);
    float var = SS * (1.f / 16384.f) - mean * mean;
    float se = bn_scale[oc] / sqrtf(var + 1e-5f);
    stats[oc * 2] = se;
    stats[oc * 2 + 1] = bn_bias[oc] - mean * se;
  }
}

// ---------------- normalize + relu + gamma*y + x ----------------
__global__ __launch_bounds__(256) void final_kernel(const float* __restrict__ y,
                                                    const float* __restrict__ x,
                                                    const float* __restrict__ stats,
                                                    const float* __restrict__ gamma,
                                                    float* __restrict__ outp) {
  int b = blockIdx.x;
  int c = b & 511;
  int t = threadIdx.x;
  float se = stats[c * 2], sh = stats[c * 2 + 1], g = gamma[0];
  float4 yv = ((const float4*)(y + (size_t)b * 1024))[t];
  float4 xv = ((const float4*)(x + (size_t)b * 1024))[t];
  float4 o;
  o.x = g * fmaxf(yv.x * se + sh, 0.f) + xv.x;
  o.y = g * fmaxf(yv.y * se + sh, 0.f) + xv.y;
  o.z = g * fmaxf(yv.z * se + sh, 0.f) + xv.z;
  o.w = g * fmaxf(yv.w * se + sh, 0.f) + xv.w;
  ((float4*)(outp + (size_t)b * 1024))[t] = o;
}

extern "C" void kernel_launch(void* const* d_in, const int* in_sizes, int n_in,
                              void* d_out, int out_size, void* d_ws, size_t ws_size,
                              hipStream_t stream) {
  const float* x        = (const float*)d_in[0];
  const float* rce_w    = (const float*)d_in[1];
  const float* rce_b    = (const float*)d_in[2];
  const float* q_w      = (const float*)d_in[3];
  const float* q_b      = (const float*)d_in[4];
  const float* k_w      = (const float*)d_in[5];
  const float* k_b      = (const float*)d_in[6];
  const float* value_w  = (const float*)d_in[7];
  const float* value_b  = (const float*)d_in[8];
  const float* fw       = (const float*)d_in[9];
  const float* bn_scale = (const float*)d_in[10];
  const float* bn_bias  = (const float*)d_in[11];
  const float* gamma    = (const float*)d_in[12];

  float* ws    = (float*)d_ws;
  float* pv    = ws + OFF_PV;
  unsigned short* pvh = (unsigned short*)(ws + OFF_PVH);
  float* ybuf  = ws + OFF_Y;
  unsigned short* xTbuf = (unsigned short*)(ws + OFF_Y);  // union: dead before energy
  unsigned short* Pbuf  = (unsigned short*)(ws + OFF_Y);  // union: dead before convmm
  unsigned short* catp = (unsigned short*)(ws + OFF_CATP);
  float* qT    = ws + OFF_QT;
  float* kT    = ws + OFF_KT;
  float* pool  = ws + OFF_POOL;
  float* feat  = ws + OFF_FEAT;
  unsigned short* Aw = (unsigned short*)(ws + OFF_AW);
  float* means = ws + OFF_MEANS;
  float* stats = ws + OFF_STAT;
  unsigned short* vwh = (unsigned short*)(ws + OFF_VWH);
  float* outp  = (float*)d_out;

  hipLaunchKernelGGL(pool_kernel,    dim3(8192),       dim3(256), 0, stream, x, pool);
  hipLaunchKernelGGL(feat_kernel,    dim3(128, 16),    dim3(64),  0, stream, pool, rce_w, rce_b, feat);
  hipLaunchKernelGGL(qk2_kernel,     dim3(16),         dim3(256), 0, stream, feat, q_w, q_b, k_w, k_b, qT, kT);
  hipLaunchKernelGGL(xcast_kernel,   dim3(16, 8, 16),  dim3(256), 0, stream, x, xTbuf);
  hipLaunchKernelGGL(vwcast_kernel,  dim3(256),        dim3(256), 0, stream, value_w, vwh);
  hipLaunchKernelGGL(pvmm2_kernel,   dim3(16, 16),     dim3(256), 0, stream, vwh, xTbuf, value_b, pv, pvh);
  hipLaunchKernelGGL(mean_kernel,    dim3(128, 16),    dim3(256), 0, stream, pv, means);
  hipLaunchKernelGGL(fillcat_kernel, dim3(18496),      dim3(128), 0, stream, means, catp);
  hipLaunchKernelGGL(wcast_kernel,   dim3(512),        dim3(256), 0, stream, fw, Aw);
  hipLaunchKernelGGL(energy_kernel,  dim3(32, 16),     dim3(256), 0, stream, qT, kT, Pbuf, 0);
  hipLaunchKernelGGL(pvmm_kernel,    dim3(16, 16),     dim3(256), 0, stream, pvh, Pbuf, catp, 0);
  hipLaunchKernelGGL(energy_kernel,  dim3(32, 16),     dim3(256), 0, stream, qT, kT, Pbuf, 1);
  hipLaunchKernelGGL(pvmm_kernel,    dim3(16, 16),     dim3(256), 0, stream, pvh, Pbuf, catp, 1);
  hipLaunchKernelGGL(convmm_kernel,  dim3(128, 4),     dim3(256), 0, stream, Aw, catp, ybuf);
  hipLaunchKernelGGL(bnstat_kernel,  dim3(512),        dim3(256), 0, stream, ybuf, bn_scale, bn_bias, stats);
  hipLaunchKernelGGL(final_kernel,   dim3(8192),       dim3(256), 0, stream, ybuf, x, stats, gamma, outp);
}

// Round 5
// 286.477 us; speedup vs baseline: 4.7299x; 1.2875x over previous
//
#include <hip/hip_runtime.h>
#include <hip/hip_fp16.h>
#include <math.h>

// n=16, C=512, c4=128, qk=16, H=W=32, L=1024. fp32 in/out.
// conv + attention (fused flash, QK^T and PV both MFMA) + value-proj via MFMA.
//
// ws layout (float offsets), total 17,259,520 floats = 69.0 MB:
#define OFF_PV    0u          // (unused spare)
#define OFF_PVH   2097152u    // pvh   [16][128][1024] f16
#define OFF_Y     3145728u    // y     [16][512][1024] f32
                              //   UNION: xT f16 [16][1024][512] (dead before convmm)
#define OFF_CATP  11534336u   // catT_p[16][1156][384] bf16 (pixel-major, 34x34 zero-padded)
#define OFF_QH    15085568u   // qh    [2][16][1024][16] f16
#define OFF_KH    15347712u   // kh    [2][16][1024][16] f16
#define OFF_POOL  16134144u   // pool  [16][512][20] f32
#define OFF_FEAT  16297984u   // feat  [16][128][20] f32
#define OFF_AW    16338944u   // Aw    [512][3456] bf16 (k = (ky*3+kx)*384+ic)
#define OFF_MEANS 17223680u   // means [16][128] f32
#define OFF_STAT  17225728u   // stats [512][2] f32
#define OFF_VWH   17226752u   // vwh   [128][512] f16

typedef __bf16 bf16x8 __attribute__((ext_vector_type(8)));
typedef _Float16 f16x8 __attribute__((ext_vector_type(8)));
typedef _Float16 f16x4 __attribute__((ext_vector_type(4)));
typedef float f32x4 __attribute__((ext_vector_type(4)));

__device__ __forceinline__ unsigned short f2bf(float f) {
  unsigned int u = __float_as_uint(f);
  unsigned int r = u + 0x7fff + ((u >> 16) & 1);   // RNE
  return (unsigned short)(r >> 16);
}

__device__ __forceinline__ unsigned short f2h(float f) {
  union { _Float16 h; unsigned short u; } cv;
  cv.h = (_Float16)f;
  return cv.u;
}

__device__ __forceinline__ void gload_lds16(const void* g, void* l) {
  __builtin_amdgcn_global_load_lds(
      (const __attribute__((address_space(1))) unsigned int*)g,
      (__attribute__((address_space(3))) unsigned int*)l, 16, 0, 0);
}

// ---------------- pooling: pooled4 (8x8 blocks) + pooled2 derived ----------------
__global__ __launch_bounds__(256) void pool_kernel(const float* __restrict__ x,
                                                   float* __restrict__ pool) {
  int b = blockIdx.x;            // n*512 + c
  int t = threadIdx.x;
  const float4* xp = (const float4*)(x + (size_t)b * 1024);
  float4 v = xp[t];
  float s4 = v.x + v.y + v.z + v.w;
  __shared__ float sm[256];
  __shared__ float p4s[16];
  sm[t] = s4;
  __syncthreads();
  if (t < 16) {
    int br = t >> 2, bc = t & 3;
    float s = 0.f;
#pragma unroll
    for (int rr = 0; rr < 8; ++rr) {
      int base = br * 64 + rr * 8 + bc * 2;
      s += sm[base] + sm[base + 1];
    }
    s *= (1.f / 64.f);
    p4s[t] = s;
    pool[(size_t)b * 20 + t] = s;
  }
  __syncthreads();
  if (t < 4) {
    int i2 = t >> 1, j2 = t & 1;
    float s = (p4s[(2*i2)*4 + 2*j2]     + p4s[(2*i2)*4 + 2*j2 + 1] +
               p4s[(2*i2+1)*4 + 2*j2]   + p4s[(2*i2+1)*4 + 2*j2 + 1]) * 0.25f;
    pool[(size_t)b * 20 + 16 + t] = s;
  }
}

// ---------------- feat = rce_w[i] @ pooled_i + rce_b[i] (scales sz=2,4) ----------------
__global__ __launch_bounds__(64) void feat_kernel(const float* __restrict__ pool,
                                                  const float* __restrict__ rce_w,
                                                  const float* __restrict__ rce_b,
                                                  float* __restrict__ feat) {
  int o = blockIdx.x, n = blockIdx.y, t = threadIdx.x;
  float part[20];
#pragma unroll
  for (int j = 0; j < 20; ++j) part[j] = 0.f;
  for (int c = t; c < 512; c += 64) {
    const float* pl = pool + ((size_t)n * 512 + c) * 20;
    float w2 = rce_w[(size_t)(128 + o) * 512 + c];
    float w4 = rce_w[(size_t)(256 + o) * 512 + c];
#pragma unroll
    for (int j = 0; j < 4; ++j)  part[j]     += w2 * pl[16 + j];
#pragma unroll
    for (int j = 0; j < 16; ++j) part[4 + j] += w4 * pl[j];
  }
  __shared__ float red[64][20];
#pragma unroll
  for (int j = 0; j < 20; ++j) red[t][j] = part[j];
  __syncthreads();
  if (t < 20) {
    float s = 0.f;
    for (int i = 0; i < 64; ++i) s += red[i][t];
    s += (t < 4) ? rce_b[128 + o] : rce_b[256 + o];
    feat[((size_t)n * 128 + o) * 20 + t] = s;
  }
}

// ------------- q/k fields, f16, layout [s][n][l][16] for MFMA attention -------------
__global__ __launch_bounds__(256) void qk2_kernel(const float* __restrict__ feat,
                                                  const float* __restrict__ q_w,
                                                  const float* __restrict__ q_b,
                                                  const float* __restrict__ k_w,
                                                  const float* __restrict__ k_b,
                                                  unsigned short* __restrict__ qh,
                                                  unsigned short* __restrict__ kh) {
  int n = blockIdx.x, t = threadIdx.x;
  __shared__ float fL[128 * 20];
  __shared__ float GH[2][16][20];
  for (int idx = t; idx < 2560; idx += 256) fL[idx] = feat[(size_t)n * 2560 + idx];
  __syncthreads();
  for (int idx = t; idx < 640; idx += 256) {
    int which = idx / 320, rem = idx % 320, qc = rem / 20, j = rem % 20;
    const float* w = which ? k_w : q_w;
    float s = which ? k_b[qc] : q_b[qc];
    for (int c = 0; c < 128; ++c) s += w[qc * 128 + c] * fL[c * 20 + j];
    GH[which][qc][j] = s;
  }
  __syncthreads();
  for (int it = 0; it < 16; ++it) {
    int row = t + 256 * it;              // 4096 rows: [s][which][l]
    int l = row & 1023, which = (row >> 10) & 1, s = row >> 11;
    int ry = l >> 5, cx = l & 31;
    int t0, t1, t2, t3;
    float w0, w1, w2, w3;
    if (s == 0) {
      float a = ry * (1.0f / 31.0f), b = cx * (1.0f / 31.0f);
      t0 = 0; t1 = 1; t2 = 2; t3 = 3;
      w0 = (1.f - a) * (1.f - b); w1 = (1.f - a) * b;
      w2 = a * (1.f - b);         w3 = a * b;
    } else {
      float pr = ry * (3.0f / 31.0f);
      int lr = (int)pr; if (lr > 2) lr = 2;
      float fr = pr - (float)lr;
      float pc = cx * (3.0f / 31.0f);
      int lc = (int)pc; if (lc > 2) lc = 2;
      float fc = pc - (float)lc;
      int base = 4 + lr * 4 + lc;
      t0 = base; t1 = base + 1; t2 = base + 4; t3 = base + 5;
      w0 = (1.f - fr) * (1.f - fc); w1 = (1.f - fr) * fc;
      w2 = fr * (1.f - fc);         w3 = fr * fc;
    }
    float val[16];
#pragma unroll
    for (int qc = 0; qc < 16; ++qc) {
      const float* G = GH[which][qc];
      val[qc] = w0 * G[t0] + w1 * G[t1] + w2 * G[t2] + w3 * G[t3];
    }
    unsigned short* dst = (which ? kh : qh) + (((size_t)(s * 16 + n) * 1024 + l) * 16);
#pragma unroll
    for (int u = 0; u < 4; ++u)
      *(ushort4*)(dst + 4 * u) = make_ushort4(f2h(val[4*u]), f2h(val[4*u+1]),
                                              f2h(val[4*u+2]), f2h(val[4*u+3]));
  }
}

// ---------------- xT[n][l][c] = f16(x[n][c][l])  (LDS tile transpose) ----------------
__global__ __launch_bounds__(256) void xcast_kernel(const float* __restrict__ x,
                                                    unsigned short* __restrict__ xT) {
  int lt = blockIdx.x, ct = blockIdx.y, n = blockIdx.z;
  int l0 = lt * 64, c0 = ct * 64, t = threadIdx.x;
  __shared__ float tile[64 * 65];
#pragma unroll
  for (int i = 0; i < 16; ++i) {
    int idx = t + 256 * i;
    int c = idx >> 6, l = idx & 63;
    tile[c * 65 + l] = x[((size_t)n * 512 + c0 + c) * 1024 + l0 + l];
  }
  __syncthreads();
#pragma unroll
  for (int i = 0; i < 16; ++i) {
    int idx = t + 256 * i;
    int l = idx >> 6, c = idx & 63;
    xT[((size_t)n * 1024 + l0 + l) * 512 + c0 + c] = f2h(tile[c * 65 + l]);
  }
}

// ---------------- vwh = f16(value_w) ----------------
__global__ __launch_bounds__(256) void vwcast_kernel(const float* __restrict__ vw,
                                                     unsigned short* __restrict__ vwh) {
  int i = blockIdx.x * 256 + threadIdx.x;
  vwh[i] = f2h(vw[i]);
}

// ------------- value-proj GEMM (f16 MFMA): pvh[c,l] = f16(sum_k vwh[c,k] xT[n][l][k] + vb) -------------
__global__ __launch_bounds__(256) void pvmm2_kernel(const unsigned short* __restrict__ vwh,
                                                    const unsigned short* __restrict__ xT,
                                                    const float* __restrict__ vb,
                                                    unsigned short* __restrict__ pvh) {
  int l0 = blockIdx.x * 64;
  int n = blockIdx.y;
  int t = threadIdx.x, lane = t & 63, wv = t >> 6;
  int wm = (wv & 1) * 64, wn = (wv >> 1) * 32;

  __shared__ short Asm[128 * 32];
  __shared__ short Bsm[64 * 32];

  int ar0 = t >> 2,        aq0 = (t & 3) ^ ((ar0 >> 1) & 3);
  int idx1 = t + 256; int ar1 = idx1 >> 2, aq1 = (idx1 & 3) ^ ((ar1 >> 1) & 3);
  int br  = t >> 2,        bq  = (t & 3) ^ ((br >> 1) & 3);
  const unsigned short* Ab0 = vwh + (size_t)ar0 * 512 + aq0 * 8;
  const unsigned short* Ab1 = vwh + (size_t)ar1 * 512 + aq1 * 8;
  const unsigned short* Bb  = xT + ((size_t)n * 1024 + l0 + br) * 512 + bq * 8;
  char* ldsA = (char*)Asm;
  char* ldsB = (char*)Bsm;
  int wvoff = wv * 1024;
  int r15 = lane & 15, kg = lane >> 4;
  int kq = kg ^ ((r15 >> 1) & 3);

  f32x4 acc[4][2];
#pragma unroll
  for (int i = 0; i < 4; ++i)
#pragma unroll
    for (int j = 0; j < 2; ++j) acc[i][j] = (f32x4){0.f, 0.f, 0.f, 0.f};

  for (int k0 = 0; k0 < 512; k0 += 32) {
    __syncthreads();
    gload_lds16(Ab0 + k0, ldsA + wvoff);
    gload_lds16(Ab1 + k0, ldsA + 4096 + wvoff);
    gload_lds16(Bb + k0,  ldsB + wvoff);
    __syncthreads();
    f16x8 af[4], bfr[2];
#pragma unroll
    for (int mt2 = 0; mt2 < 4; ++mt2)
      af[mt2] = *(const f16x8*)&Asm[(wm + mt2 * 16 + r15) * 32 + kq * 8];
#pragma unroll
    for (int nt2 = 0; nt2 < 2; ++nt2)
      bfr[nt2] = *(const f16x8*)&Bsm[(wn + nt2 * 16 + r15) * 32 + kq * 8];
#pragma unroll
    for (int mt2 = 0; mt2 < 4; ++mt2)
#pragma unroll
      for (int nt2 = 0; nt2 < 2; ++nt2)
        acc[mt2][nt2] = __builtin_amdgcn_mfma_f32_16x16x32_f16(af[mt2], bfr[nt2], acc[mt2][nt2], 0, 0, 0);
  }

  int c_lo = wm + (lane >> 4) * 4;
  int l_lo = wn + (lane & 15);
#pragma unroll
  for (int mt2 = 0; mt2 < 4; ++mt2)
#pragma unroll
    for (int nt2 = 0; nt2 < 2; ++nt2) {
      int l = l0 + l_lo + nt2 * 16;
#pragma unroll
      for (int r = 0; r < 4; ++r) {
        int c = c_lo + mt2 * 16 + r;
        pvh[((size_t)n * 128 + c) * 1024 + l] = f2h(acc[mt2][nt2][r] + vb[c]);
      }
    }
}

// ---------------- means[n][c] = mean_l pvh[n][c][l]  (sz=1 branch is constant) ----------------
__global__ __launch_bounds__(256) void mean_kernel(const unsigned short* __restrict__ pvh,
                                                   float* __restrict__ means) {
  int c = blockIdx.x, n = blockIdx.y, t = threadIdx.x;
  f16x4 v = ((const f16x4*)(pvh + ((size_t)n * 128 + c) * 1024))[t];
  float s = (float)v[0] + (float)v[1] + (float)v[2] + (float)v[3];
  for (int o = 32; o > 0; o >>= 1) s += __shfl_down(s, o);
  __shared__ float wsum[4];
  if ((t & 63) == 0) wsum[t >> 6] = s;
  __syncthreads();
  if (t == 0) means[n * 128 + c] = (wsum[0] + wsum[1] + wsum[2] + wsum[3]) * (1.f / 1024.f);
}

// ---- fill catT_p: border rows all-zero; interior rows ch0..127 = means (bf16) ----
__global__ __launch_bounds__(128) void fillcat_kernel(const float* __restrict__ means,
                                                      unsigned short* __restrict__ catp) {
  int b = blockIdx.x;            // n*1156 + pp
  int n = b / 1156, pp = b % 1156;
  int py = pp / 34, px = pp % 34;
  int t = threadIdx.x;
  unsigned short* row = catp + (size_t)b * 384;
  if (py == 0 || py == 33 || px == 0 || px == 33) {
    row[t] = 0; row[t + 128] = 0; row[t + 256] = 0;
  } else {
    row[t] = f2bf(means[n * 128 + t]);
  }
}

// ---------------- weight reorder+cast ----------------
__global__ __launch_bounds__(256) void wcast_kernel(const float* __restrict__ fw,
                                                    unsigned short* __restrict__ Aw) {
  int oc = blockIdx.x, t = threadIdx.x;
  for (int j = t; j < 3456; j += 256) {
    int seg = j / 384, ic = j % 384;
    Aw[(size_t)oc * 3456 + j] = f2bf(fw[(size_t)oc * 3456 + ic * 9 + seg]);
  }
}

// ------------- fused flash attention (MFMA QK^T + MFMA PV, no P in HBM) -------------
// block: (n, sc, 64 m-pixels). S = qk^T via 16x16x32_f16 with K zero-padded (qk=16);
// U = exp(S) (no max-sub: |S|<0.5 by construction) -> LDS; PV accumulates via MFMA;
// normalization deferred to epilogue as 1/rowsum.
__global__ __launch_bounds__(256) void fattn_kernel(const unsigned short* __restrict__ qh,
                                                    const unsigned short* __restrict__ kh,
                                                    const unsigned short* __restrict__ pvh,
                                                    unsigned short* __restrict__ catp) {
  int m0 = blockIdx.x * 64;
  int n = blockIdx.y, sc = blockIdx.z;
  int t = threadIdx.x, lane = t & 63, wv = t >> 6;
  int wc = (wv >> 1) * 64;      // c base (0/64)
  int wm2 = (wv & 1) * 32;      // m base within block tile (0/32)
  int r15 = lane & 15, kg = lane >> 4;
  int kq = kg ^ ((r15 >> 1) & 3);

  const unsigned short* qb  = qh + ((size_t)(sc * 16 + n) * 1024 + m0 + wv * 16) * 16;
  const unsigned short* kb  = kh + ((size_t)(sc * 16 + n) * 1024) * 16;
  const unsigned short* pvb = pvh + (size_t)n * 128 * 1024;

  __shared__ short PVs[2 * 128 * 32];   // two 32-l subtiles, 64B rows, XOR-chunk image
  __shared__ _Float16 Us[64 * 72];      // U[m][l] f16, pitch 72 (16B-aligned rows)
  __shared__ float rsum[64];

  f16x8 zf = {0, 0, 0, 0, 0, 0, 0, 0};
  // q A-frag (fixed per wave): rows m0+wv*16+r15, K zero-padded to 32
  f16x8 qa = (kg < 2) ? *(const f16x8*)(qb + r15 * 16 + kg * 8) : zf;

  // pv staging addresses (proven 4-chunk XOR pattern, 64B rows)
  int prow = t >> 2;
  int aq = (t & 3) ^ ((prow >> 1) & 3);
  const unsigned short* Pb0 = pvb + (size_t)prow * 1024 + aq * 8;
  const unsigned short* Pb1 = pvb + (size_t)(prow + 64) * 1024 + aq * 8;
  char* ldsPV = (char*)PVs;
  int wvoff = wv * 1024;

  f32x4 acc[4][2];                      // [c-tile][m-tile]
#pragma unroll
  for (int i = 0; i < 4; ++i)
#pragma unroll
    for (int j = 0; j < 2; ++j) acc[i][j] = (f32x4){0.f, 0.f, 0.f, 0.f};
  float rs[4] = {0.f, 0.f, 0.f, 0.f};

  for (int it = 0; it < 16; ++it) {
    int l0 = it * 64;
    __syncthreads();                    // prev-iter PV/U consumers done
    gload_lds16(Pb0 + l0,      ldsPV + wvoff);
    gload_lds16(Pb1 + l0,      ldsPV + 4096 + wvoff);
    gload_lds16(Pb0 + l0 + 32, ldsPV + 8192 + wvoff);
    gload_lds16(Pb1 + l0 + 32, ldsPV + 12288 + wvoff);

    // S strip for this wave: rows [wv*16, +16) x 64 l (4 MFMAs), k frags from L2
    f32x4 sacc[4];
#pragma unroll
    for (int lt = 0; lt < 4; ++lt) {
      f16x8 kbf = (kg < 2)
        ? *(const f16x8*)(kb + (size_t)(l0 + lt * 16 + r15) * 16 + kg * 8) : zf;
      sacc[lt] = __builtin_amdgcn_mfma_f32_16x16x32_f16(qa, kbf, (f32x4){0.f,0.f,0.f,0.f}, 0, 0, 0);
    }
    // exp + U write + rowsum partials (C layout: l=r15, m=kg*4+r)
#pragma unroll
    for (int lt = 0; lt < 4; ++lt)
#pragma unroll
      for (int r = 0; r < 4; ++r) {
        float e = __expf(sacc[lt][r]);
        Us[(wv * 16 + kg * 4 + r) * 72 + lt * 16 + r15] = (_Float16)e;
        rs[r] += e;
      }
    __syncthreads();                    // U visible + pv staged (vmcnt drained)

    // PV MFMAs: C[c][m] += pv[c][l] * U[m][l], K=64 as 2 k-steps
#pragma unroll
    for (int ks = 0; ks < 2; ++ks) {
      f16x8 bfr[2];
#pragma unroll
      for (int nt = 0; nt < 2; ++nt)
        bfr[nt] = *(const f16x8*)&Us[(wm2 + nt * 16 + r15) * 72 + ks * 32 + kg * 8];
#pragma unroll
      for (int ct = 0; ct < 4; ++ct) {
        f16x8 af = *(const f16x8*)&PVs[ks * 4096 + (wc + ct * 16 + r15) * 32 + kq * 8];
#pragma unroll
        for (int nt = 0; nt < 2; ++nt)
          acc[ct][nt] = __builtin_amdgcn_mfma_f32_16x16x32_f16(af, bfr[nt], acc[ct][nt], 0, 0, 0);
      }
    }
  }

  // finalize rowsums: reduce over the 16-lane l groups, publish to LDS
#pragma unroll
  for (int r = 0; r < 4; ++r) {
    rs[r] += __shfl_xor(rs[r], 1);
    rs[r] += __shfl_xor(rs[r], 2);
    rs[r] += __shfl_xor(rs[r], 4);
    rs[r] += __shfl_xor(rs[r], 8);
  }
  if (r15 == 0) {
#pragma unroll
    for (int r = 0; r < 4; ++r) rsum[wv * 16 + kg * 4 + r] = rs[r];
  }
  __syncthreads();

  // epilogue: divide by rowsum, write bf16 pixel-major into catp
#pragma unroll
  for (int nt = 0; nt < 2; ++nt) {
    float inv = 1.f / rsum[wm2 + nt * 16 + r15];
    int pix = m0 + wm2 + nt * 16 + r15;
    unsigned short* ob = catp + ((size_t)n * 1156 + ((pix >> 5) + 1) * 34 + (pix & 31) + 1) * 384
                       + 128 + sc * 128 + wc + kg * 4;
#pragma unroll
    for (int ct = 0; ct < 4; ++ct) {
      ushort4 o = make_ushort4(f2bf(acc[ct][nt][0] * inv), f2bf(acc[ct][nt][1] * inv),
                               f2bf(acc[ct][nt][2] * inv), f2bf(acc[ct][nt][3] * inv));
      *(ushort4*)(ob + ct * 16) = o;
    }
  }
}

// ---------------- fusion conv as implicit GEMM (bf16 MFMA) ----------------
__global__ __launch_bounds__(256) void convmm_kernel(const unsigned short* __restrict__ Aw,
                                                     const unsigned short* __restrict__ catp,
                                                     float* __restrict__ y) {
  int ntile = blockIdx.x;
  int n = ntile >> 3, y0 = (ntile & 7) * 4;
  int m0 = blockIdx.y * 128;
  int t = threadIdx.x;
  int lane = t & 63, wv = t >> 6;
  int wm = (wv & 1) * 64, wn = (wv >> 1) * 64;

  __shared__ short Asm[128 * 32];
  __shared__ short Bsm[128 * 32];

  int idx0 = t, idx1 = t + 256;
  int ar0 = idx0 >> 2, aq0 = (idx0 & 3) ^ ((ar0 >> 1) & 3);
  int ar1 = idx1 >> 2, aq1 = (idx1 & 3) ^ ((ar1 >> 1) & 3);
  size_t abase0 = (size_t)(m0 + ar0) * 3456 + aq0 * 8;
  size_t abase1 = (size_t)(m0 + ar1) * 3456 + aq1 * 8;
  size_t bbase0 = ((size_t)n * 1156 + (size_t)(y0 + (ar0 >> 5)) * 34 + (ar0 & 31)) * 384 + aq0 * 8;
  size_t bbase1 = ((size_t)n * 1156 + (size_t)(y0 + (ar1 >> 5)) * 34 + (ar1 & 31)) * 384 + aq1 * 8;
  char* ldsA = (char*)Asm;
  char* ldsB = (char*)Bsm;
  int wvoff = wv * 1024;

  int r15 = lane & 15, kg = lane >> 4;
  int kq = kg ^ ((r15 >> 1) & 3);

  f32x4 acc[4][4];
#pragma unroll
  for (int i = 0; i < 4; ++i)
#pragma unroll
    for (int j = 0; j < 4; ++j) acc[i][j] = (f32x4){0.f, 0.f, 0.f, 0.f};

  for (int seg = 0; seg < 9; ++seg) {
    size_t boffseg = (size_t)((seg / 3) * 34 + (seg % 3)) * 384;
    size_t akkseg = (size_t)seg * 384;
    for (int icc = 0; icc < 12; ++icc) {
      size_t akk = akkseg + icc * 32;
      size_t boff = boffseg + icc * 32;
      __syncthreads();
      gload_lds16(Aw + abase0 + akk,   ldsA + wvoff);
      gload_lds16(Aw + abase1 + akk,   ldsA + 4096 + wvoff);
      gload_lds16(catp + bbase0 + boff, ldsB + wvoff);
      gload_lds16(catp + bbase1 + boff, ldsB + 4096 + wvoff);
      __syncthreads();
      bf16x8 af[4], bf[4];
#pragma unroll
      for (int mt = 0; mt < 4; ++mt)
        af[mt] = *(const bf16x8*)&Asm[(wm + mt * 16 + r15) * 32 + kq * 8];
#pragma unroll
      for (int nt = 0; nt < 4; ++nt)
        bf[nt] = *(const bf16x8*)&Bsm[(wn + nt * 16 + r15) * 32 + kq * 8];
#pragma unroll
      for (int mt = 0; mt < 4; ++mt)
#pragma unroll
        for (int nt = 0; nt < 4; ++nt)
          acc[mt][nt] = __builtin_amdgcn_mfma_f32_16x16x32_bf16(af[mt], bf[nt], acc[mt][nt], 0, 0, 0);
    }
  }

  int pixbase = (ntile & 7) * 128 + wn + (lane & 15);
  int ocbase = m0 + wm + (lane >> 4) * 4;
#pragma unroll
  for (int mt = 0; mt < 4; ++mt)
#pragma unroll
    for (int nt = 0; nt < 4; ++nt) {
      int oc = ocbase + mt * 16;
      int pix = pixbase + nt * 16;
      float* yp = y + ((size_t)n * 512 + oc) * 1024 + pix;
#pragma unroll
      for (int r = 0; r < 4; ++r) yp[(size_t)r * 1024] = acc[mt][nt][r];
    }
}

// ---------------- BN batch stats per channel ----------------
__global__ __launch_bounds__(256) void bnstat_kernel(const float* __restrict__ y,
                                                     const float* __restrict__ bn_scale,
                                                     const float* __restrict__ bn_bias,
                                                     float* __restrict__ stats) {
  int oc = blockIdx.x, t = threadIdx.x;
  float s = 0.f, ss = 0.f;
  for (int n = 0; n < 16; ++n) {
    float4 v = ((const float4*)(y + ((size_t)n * 512 + oc) * 1024))[t];
    s  += v.x + v.y + v.z + v.w;
    ss += v.x * v.x + v.y * v.y + v.z * v.z + v.w * v.w;
  }
  for (int o = 32; o > 0; o >>= 1) {
    s  += __shfl_down(s, o);
    ss += __shfl_down(ss, o);
  }
  __shared__ float rs[4], rss[4];
  if ((t & 63) == 0) { rs[t >> 6] = s; rss[t >> 6] = ss; }
  __syncthreads();
  if (t == 0) {
    float S = rs[0] + rs[1] + rs[2] + rs[3];
    float SS = rss[0] + rss[1] + rss[2] + rss[3];
    float mean = S * (1.f / 16384.f);
    float var = SS * (1.f / 16384.f) - mean * mean;
    float se = bn_scale[oc] / sqrtf(var + 1e-5f);
    stats[oc * 2] = se;
    stats[oc * 2 + 1] = bn_bias[oc] - mean * se;
  }
}

// ---------------- normalize + relu + gamma*y + x ----------------
__global__ __launch_bounds__(256) void final_kernel(const float* __restrict__ y,
                                                    const float* __restrict__ x,
                                                    const float* __restrict__ stats,
                                                    const float* __restrict__ gamma,
                                                    float* __restrict__ outp) {
  int b = blockIdx.x;
  int c = b & 511;
  int t = threadIdx.x;
  float se = stats[c * 2], sh = stats[c * 2 + 1], g = gamma[0];
  float4 yv = ((const float4*)(y + (size_t)b * 1024))[t];
  float4 xv = ((const float4*)(x + (size_t)b * 1024))[t];
  float4 o;
  o.x = g * fmaxf(yv.x * se + sh, 0.f) + xv.x;
  o.y = g * fmaxf(yv.y * se + sh, 0.f) + xv.y;
  o.z = g * fmaxf(yv.z * se + sh, 0.f) + xv.z;
  o.w = g * fmaxf(yv.w * se + sh, 0.f) + xv.w;
  ((float4*)(outp + (size_t)b * 1024))[t] = o;
}

extern "C" void kernel_launch(void* const* d_in, const int* in_sizes, int n_in,
                              void* d_out, int out_size, void* d_ws, size_t ws_size,
                              hipStream_t stream) {
  const float* x        = (const float*)d_in[0];
  const float* rce_w    = (const float*)d_in[1];
  const float* rce_b    = (const float*)d_in[2];
  const float* q_w      = (const float*)d_in[3];
  const float* q_b      = (const float*)d_in[4];
  const float* k_w      = (const float*)d_in[5];
  const float* k_b      = (const float*)d_in[6];
  const float* value_w  = (const float*)d_in[7];
  const float* value_b  = (const float*)d_in[8];
  const float* fw       = (const float*)d_in[9];
  const float* bn_scale = (const float*)d_in[10];
  const float* bn_bias  = (const float*)d_in[11];
  const float* gamma    = (const float*)d_in[12];

  float* ws    = (float*)d_ws;
  unsigned short* pvh = (unsigned short*)(ws + OFF_PVH);
  float* ybuf  = ws + OFF_Y;
  unsigned short* xTbuf = (unsigned short*)(ws + OFF_Y);  // union: dead before convmm
  unsigned short* catp = (unsigned short*)(ws + OFF_CATP);
  unsigned short* qh   = (unsigned short*)(ws + OFF_QH);
  unsigned short* kh   = (unsigned short*)(ws + OFF_KH);
  float* pool  = ws + OFF_POOL;
  float* feat  = ws + OFF_FEAT;
  unsigned short* Aw = (unsigned short*)(ws + OFF_AW);
  float* means = ws + OFF_MEANS;
  float* stats = ws + OFF_STAT;
  unsigned short* vwh = (unsigned short*)(ws + OFF_VWH);
  float* outp  = (float*)d_out;

  hipLaunchKernelGGL(pool_kernel,    dim3(8192),       dim3(256), 0, stream, x, pool);
  hipLaunchKernelGGL(feat_kernel,    dim3(128, 16),    dim3(64),  0, stream, pool, rce_w, rce_b, feat);
  hipLaunchKernelGGL(qk2_kernel,     dim3(16),         dim3(256), 0, stream, feat, q_w, q_b, k_w, k_b, qh, kh);
  hipLaunchKernelGGL(xcast_kernel,   dim3(16, 8, 16),  dim3(256), 0, stream, x, xTbuf);
  hipLaunchKernelGGL(vwcast_kernel,  dim3(256),        dim3(256), 0, stream, value_w, vwh);
  hipLaunchKernelGGL(pvmm2_kernel,   dim3(16, 16),     dim3(256), 0, stream, vwh, xTbuf, value_b, pvh);
  hipLaunchKernelGGL(mean_kernel,    dim3(128, 16),    dim3(256), 0, stream, pvh, means);
  hipLaunchKernelGGL(fillcat_kernel, dim3(18496),      dim3(128), 0, stream, means, catp);
  hipLaunchKernelGGL(wcast_kernel,   dim3(512),        dim3(256), 0, stream, fw, Aw);
  hipLaunchKernelGGL(fattn_kernel,   dim3(16, 16, 2),  dim3(256), 0, stream, qh, kh, pvh, catp);
  hipLaunchKernelGGL(convmm_kernel,  dim3(128, 4),     dim3(256), 0, stream, Aw, catp, ybuf);
  hipLaunchKernelGGL(bnstat_kernel,  dim3(512),        dim3(256), 0, stream, ybuf, bn_scale, bn_bias, stats);
  hipLaunchKernelGGL(final_kernel,   dim3(8192),       dim3(256), 0, stream, ybuf, x, stats, gamma, outp);
}

// Round 7
// 264.884 us; speedup vs baseline: 5.1154x; 1.0815x over previous
//
#include <hip/hip_runtime.h>
#include <hip/hip_fp16.h>
#include <math.h>

// n=16, C=512, c4=128, qk=16, H=W=32, L=1024. fp32 in/out.
// conv (K=2304, mean-channels factored out analytically) + fused flash attention
// + value-proj, all matmuls on MFMA.
//
// ws layout (float offsets):
#define OFF_COR   0u          // cor   [16][512][9] f32 (mean-channel conv contribution)
#define OFF_PVH   2097152u    // pvh   [16][128][1024] f16
#define OFF_Y     3145728u    // y     [16][512][1024] f32
                              //   UNION: xT f16 [16][1024][512] (dead before convmm)
#define OFF_CATP  11534336u   // catT_p[16][1156][256] bf16 (pixel-major, 34x34 zero-padded)
#define OFF_QH    15085568u   // qh    [2][16][1024][16] f16
#define OFF_KH    15347712u   // kh    [2][16][1024][16] f16
#define OFF_POOL  16134144u   // pool  [16][512][20] f32
#define OFF_FEAT  16297984u   // feat  [16][128][20] f32
#define OFF_AW    16338944u   // Aw    [512][2304] bf16 (k = (ky*3+kx)*256 + (ic-128))
#define OFF_MEANS 17223680u   // means [16][128] f32
#define OFF_STAT  17225728u   // stats [512][2] f32
#define OFF_VWH   17226752u   // vwh   [128][512] f16

typedef __bf16 bf16x8 __attribute__((ext_vector_type(8)));
typedef _Float16 f16x8 __attribute__((ext_vector_type(8)));
typedef _Float16 f16x4 __attribute__((ext_vector_type(4)));
typedef float f32x4 __attribute__((ext_vector_type(4)));

__device__ __forceinline__ unsigned short f2bf(float f) {
  unsigned int u = __float_as_uint(f);
  unsigned int r = u + 0x7fff + ((u >> 16) & 1);   // RNE
  return (unsigned short)(r >> 16);
}

__device__ __forceinline__ unsigned short f2h(float f) {
  union { _Float16 h; unsigned short u; } cv;
  cv.h = (_Float16)f;
  return cv.u;
}

__device__ __forceinline__ void gload_lds16(const void* g, void* l) {
  __builtin_amdgcn_global_load_lds(
      (const __attribute__((address_space(1))) unsigned int*)g,
      (__attribute__((address_space(3))) unsigned int*)l, 16, 0, 0);
}

// ---------------- pooling: pooled4 (8x8 blocks) + pooled2 derived ----------------
__global__ __launch_bounds__(256) void pool_kernel(const float* __restrict__ x,
                                                   float* __restrict__ pool) {
  int b = blockIdx.x;            // n*512 + c
  int t = threadIdx.x;
  const float4* xp = (const float4*)(x + (size_t)b * 1024);
  float4 v = xp[t];
  float s4 = v.x + v.y + v.z + v.w;
  __shared__ float sm[256];
  __shared__ float p4s[16];
  sm[t] = s4;
  __syncthreads();
  if (t < 16) {
    int br = t >> 2, bc = t & 3;
    float s = 0.f;
#pragma unroll
    for (int rr = 0; rr < 8; ++rr) {
      int base = br * 64 + rr * 8 + bc * 2;
      s += sm[base] + sm[base + 1];
    }
    s *= (1.f / 64.f);
    p4s[t] = s;
    pool[(size_t)b * 20 + t] = s;
  }
  __syncthreads();
  if (t < 4) {
    int i2 = t >> 1, j2 = t & 1;
    float s = (p4s[(2*i2)*4 + 2*j2]     + p4s[(2*i2)*4 + 2*j2 + 1] +
               p4s[(2*i2+1)*4 + 2*j2]   + p4s[(2*i2+1)*4 + 2*j2 + 1]) * 0.25f;
    pool[(size_t)b * 20 + 16 + t] = s;
  }
}

// ---------------- feat = rce_w[i] @ pooled_i + rce_b[i] (scales sz=2,4) ----------------
__global__ __launch_bounds__(64) void feat_kernel(const float* __restrict__ pool,
                                                  const float* __restrict__ rce_w,
                                                  const float* __restrict__ rce_b,
                                                  float* __restrict__ feat) {
  int o = blockIdx.x, n = blockIdx.y, t = threadIdx.x;
  float part[20];
#pragma unroll
  for (int j = 0; j < 20; ++j) part[j] = 0.f;
  for (int c = t; c < 512; c += 64) {
    const float* pl = pool + ((size_t)n * 512 + c) * 20;
    float w2 = rce_w[(size_t)(128 + o) * 512 + c];
    float w4 = rce_w[(size_t)(256 + o) * 512 + c];
#pragma unroll
    for (int j = 0; j < 4; ++j)  part[j]     += w2 * pl[16 + j];
#pragma unroll
    for (int j = 0; j < 16; ++j) part[4 + j] += w4 * pl[j];
  }
  __shared__ float red[64][20];
#pragma unroll
  for (int j = 0; j < 20; ++j) red[t][j] = part[j];
  __syncthreads();
  if (t < 20) {
    float s = 0.f;
    for (int i = 0; i < 64; ++i) s += red[i][t];
    s += (t < 4) ? rce_b[128 + o] : rce_b[256 + o];
    feat[((size_t)n * 128 + o) * 20 + t] = s;
  }
}

// ------------- q/k fields, f16, layout [s][n][l][16] for MFMA attention -------------
__global__ __launch_bounds__(256) void qk2_kernel(const float* __restrict__ feat,
                                                  const float* __restrict__ q_w,
                                                  const float* __restrict__ q_b,
                                                  const float* __restrict__ k_w,
                                                  const float* __restrict__ k_b,
                                                  unsigned short* __restrict__ qh,
                                                  unsigned short* __restrict__ kh) {
  int n = blockIdx.x, t = threadIdx.x;
  __shared__ float fL[128 * 20];
  __shared__ float GH[2][16][20];
  for (int idx = t; idx < 2560; idx += 256) fL[idx] = feat[(size_t)n * 2560 + idx];
  __syncthreads();
  for (int idx = t; idx < 640; idx += 256) {
    int which = idx / 320, rem = idx % 320, qc = rem / 20, j = rem % 20;
    const float* w = which ? k_w : q_w;
    float s = which ? k_b[qc] : q_b[qc];
    for (int c = 0; c < 128; ++c) s += w[qc * 128 + c] * fL[c * 20 + j];
    GH[which][qc][j] = s;
  }
  __syncthreads();
  for (int it = 0; it < 16; ++it) {
    int row = t + 256 * it;              // 4096 rows: [s][which][l]
    int l = row & 1023, which = (row >> 10) & 1, s = row >> 11;
    int ry = l >> 5, cx = l & 31;
    int t0, t1, t2, t3;
    float w0, w1, w2, w3;
    if (s == 0) {
      float a = ry * (1.0f / 31.0f), b = cx * (1.0f / 31.0f);
      t0 = 0; t1 = 1; t2 = 2; t3 = 3;
      w0 = (1.f - a) * (1.f - b); w1 = (1.f - a) * b;
      w2 = a * (1.f - b);         w3 = a * b;
    } else {
      float pr = ry * (3.0f / 31.0f);
      int lr = (int)pr; if (lr > 2) lr = 2;
      float fr = pr - (float)lr;
      float pc = cx * (3.0f / 31.0f);
      int lc = (int)pc; if (lc > 2) lc = 2;
      float fc = pc - (float)lc;
      int base = 4 + lr * 4 + lc;
      t0 = base; t1 = base + 1; t2 = base + 4; t3 = base + 5;
      w0 = (1.f - fr) * (1.f - fc); w1 = (1.f - fr) * fc;
      w2 = fr * (1.f - fc);         w3 = fr * fc;
    }
    float val[16];
#pragma unroll
    for (int qc = 0; qc < 16; ++qc) {
      const float* G = GH[which][qc];
      val[qc] = w0 * G[t0] + w1 * G[t1] + w2 * G[t2] + w3 * G[t3];
    }
    unsigned short* dst = (which ? kh : qh) + (((size_t)(s * 16 + n) * 1024 + l) * 16);
#pragma unroll
    for (int u = 0; u < 4; ++u)
      *(ushort4*)(dst + 4 * u) = make_ushort4(f2h(val[4*u]), f2h(val[4*u+1]),
                                              f2h(val[4*u+2]), f2h(val[4*u+3]));
  }
}

// ---------------- xT[n][l][c] = f16(x[n][c][l])  (LDS tile transpose) ----------------
__global__ __launch_bounds__(256) void xcast_kernel(const float* __restrict__ x,
                                                    unsigned short* __restrict__ xT) {
  int lt = blockIdx.x, ct = blockIdx.y, n = blockIdx.z;
  int l0 = lt * 64, c0 = ct * 64, t = threadIdx.x;
  __shared__ float tile[64 * 65];
#pragma unroll
  for (int i = 0; i < 16; ++i) {
    int idx = t + 256 * i;
    int c = idx >> 6, l = idx & 63;
    tile[c * 65 + l] = x[((size_t)n * 512 + c0 + c) * 1024 + l0 + l];
  }
  __syncthreads();
#pragma unroll
  for (int i = 0; i < 16; ++i) {
    int idx = t + 256 * i;
    int l = idx >> 6, c = idx & 63;
    xT[((size_t)n * 1024 + l0 + l) * 512 + c0 + c] = f2h(tile[c * 65 + l]);
  }
}

// ---------------- vwh = f16(value_w) ----------------
__global__ __launch_bounds__(256) void vwcast_kernel(const float* __restrict__ vw,
                                                     unsigned short* __restrict__ vwh) {
  int i = blockIdx.x * 256 + threadIdx.x;
  vwh[i] = f2h(vw[i]);
}

// ------------- value-proj GEMM (f16 MFMA): pvh[c,l] = f16(sum_k vwh[c,k] xT[n][l][k] + vb) -------------
__global__ __launch_bounds__(256) void pvmm2_kernel(const unsigned short* __restrict__ vwh,
                                                    const unsigned short* __restrict__ xT,
                                                    const float* __restrict__ vb,
                                                    unsigned short* __restrict__ pvh) {
  int l0 = blockIdx.x * 64;
  int n = blockIdx.y;
  int t = threadIdx.x, lane = t & 63, wv = t >> 6;
  int wm = (wv & 1) * 64, wn = (wv >> 1) * 32;

  __shared__ short Asm[128 * 32];
  __shared__ short Bsm[64 * 32];

  int ar0 = t >> 2,        aq0 = (t & 3) ^ ((ar0 >> 1) & 3);
  int idx1 = t + 256; int ar1 = idx1 >> 2, aq1 = (idx1 & 3) ^ ((ar1 >> 1) & 3);
  int br  = t >> 2,        bq  = (t & 3) ^ ((br >> 1) & 3);
  const unsigned short* Ab0 = vwh + (size_t)ar0 * 512 + aq0 * 8;
  const unsigned short* Ab1 = vwh + (size_t)ar1 * 512 + aq1 * 8;
  const unsigned short* Bb  = xT + ((size_t)n * 1024 + l0 + br) * 512 + bq * 8;
  char* ldsA = (char*)Asm;
  char* ldsB = (char*)Bsm;
  int wvoff = wv * 1024;
  int r15 = lane & 15, kg = lane >> 4;
  int kq = kg ^ ((r15 >> 1) & 3);

  f32x4 acc[4][2];
#pragma unroll
  for (int i = 0; i < 4; ++i)
#pragma unroll
    for (int j = 0; j < 2; ++j) acc[i][j] = (f32x4){0.f, 0.f, 0.f, 0.f};

  for (int k0 = 0; k0 < 512; k0 += 32) {
    __syncthreads();
    gload_lds16(Ab0 + k0, ldsA + wvoff);
    gload_lds16(Ab1 + k0, ldsA + 4096 + wvoff);
    gload_lds16(Bb + k0,  ldsB + wvoff);
    __syncthreads();
    f16x8 af[4], bfr[2];
#pragma unroll
    for (int mt2 = 0; mt2 < 4; ++mt2)
      af[mt2] = *(const f16x8*)&Asm[(wm + mt2 * 16 + r15) * 32 + kq * 8];
#pragma unroll
    for (int nt2 = 0; nt2 < 2; ++nt2)
      bfr[nt2] = *(const f16x8*)&Bsm[(wn + nt2 * 16 + r15) * 32 + kq * 8];
#pragma unroll
    for (int mt2 = 0; mt2 < 4; ++mt2)
#pragma unroll
      for (int nt2 = 0; nt2 < 2; ++nt2)
        acc[mt2][nt2] = __builtin_amdgcn_mfma_f32_16x16x32_f16(af[mt2], bfr[nt2], acc[mt2][nt2], 0, 0, 0);
  }

  int c_lo = wm + (lane >> 4) * 4;
  int l_lo = wn + (lane & 15);
#pragma unroll
  for (int mt2 = 0; mt2 < 4; ++mt2)
#pragma unroll
    for (int nt2 = 0; nt2 < 2; ++nt2) {
      int l = l0 + l_lo + nt2 * 16;
#pragma unroll
      for (int r = 0; r < 4; ++r) {
        int c = c_lo + mt2 * 16 + r;
        pvh[((size_t)n * 128 + c) * 1024 + l] = f2h(acc[mt2][nt2][r] + vb[c]);
      }
    }
}

// ---------------- means[n][c] = mean_l pvh[n][c][l]  (sz=1 branch is constant) ----------------
__global__ __launch_bounds__(256) void mean_kernel(const unsigned short* __restrict__ pvh,
                                                   float* __restrict__ means) {
  int c = blockIdx.x, n = blockIdx.y, t = threadIdx.x;
  f16x4 v = ((const f16x4*)(pvh + ((size_t)n * 128 + c) * 1024))[t];
  float s = (float)v[0] + (float)v[1] + (float)v[2] + (float)v[3];
  for (int o = 32; o > 0; o >>= 1) s += __shfl_down(s, o);
  __shared__ float wsum[4];
  if ((t & 63) == 0) wsum[t >> 6] = s;
  __syncthreads();
  if (t == 0) means[n * 128 + c] = (wsum[0] + wsum[1] + wsum[2] + wsum[3]) * (1.f / 1024.f);
}

// ---- basecor: cor[n][oc][a*3+b] = sum over valid taps of S[ky][kx],
//      S[ky][kx] = sum_{c<128} means[n][c] * fw[oc][c][ky][kx].
//      a/b: 0 = top/left edge (ky/kx=0 cut), 1 = interior, 2 = bottom/right edge.
__global__ __launch_bounds__(64) void basecor_kernel(const float* __restrict__ means,
                                                     const float* __restrict__ fw,
                                                     float* __restrict__ cor) {
  int oc = blockIdx.x, n = blockIdx.y, t = threadIdx.x;
  float S[9];
#pragma unroll
  for (int j = 0; j < 9; ++j) S[j] = 0.f;
  for (int c = t; c < 128; c += 64) {
    float m = means[n * 128 + c];
    const float* wp = fw + (size_t)oc * 3456 + c * 9;
#pragma unroll
    for (int j = 0; j < 9; ++j) S[j] += m * wp[j];
  }
  __shared__ float red[64][9];
  __shared__ float Sf[9];
#pragma unroll
  for (int j = 0; j < 9; ++j) red[t][j] = S[j];
  __syncthreads();
  if (t < 9) {
    float s = 0.f;
    for (int i = 0; i < 64; ++i) s += red[i][t];
    Sf[t] = s;
  }
  __syncthreads();
  if (t < 9) {
    int a = t / 3, b = t % 3;
    float s = 0.f;
#pragma unroll
    for (int ky = 0; ky < 3; ++ky) {
      if ((a == 0 && ky == 0) || (a == 2 && ky == 2)) continue;
#pragma unroll
      for (int kx = 0; kx < 3; ++kx) {
        if ((b == 0 && kx == 0) || (b == 2 && kx == 2)) continue;
        s += Sf[ky * 3 + kx];
      }
    }
    cor[((size_t)n * 512 + oc) * 9 + t] = s;
  }
}

// ---- fillcat: zero the 132 border rows of each image (256 ch each) ----
__global__ __launch_bounds__(128) void fillcat_kernel(unsigned short* __restrict__ catp) {
  int b = blockIdx.x;            // n*132 + e
  int n = b / 132, e = b % 132;
  int py, px;
  if (e < 34)       { py = 0;          px = e; }
  else if (e < 68)  { py = 33;         px = e - 34; }
  else if (e < 100) { py = e - 68 + 1; px = 0; }
  else              { py = e - 100 + 1; px = 33; }
  unsigned int* row = (unsigned int*)(catp + ((size_t)n * 1156 + py * 34 + px) * 256);
  row[threadIdx.x] = 0u;         // 128 threads x 4 B = 512 B = full row
}

// ---------------- weight reorder+cast: Aw[oc][seg*256 + (ic-128)] ----------------
__global__ __launch_bounds__(256) void wcast_kernel(const float* __restrict__ fw,
                                                    unsigned short* __restrict__ Aw) {
  int oc = blockIdx.x, t = threadIdx.x;
  for (int j = t; j < 2304; j += 256) {
    int seg = j >> 8, ic2 = j & 255;
    Aw[(size_t)oc * 2304 + j] = f2bf(fw[(size_t)oc * 3456 + (128 + ic2) * 9 + seg]);
  }
}

// ------------- fused flash attention (MFMA QK^T + MFMA PV, no P in HBM) -------------
__global__ __launch_bounds__(256) void fattn_kernel(const unsigned short* __restrict__ qh,
                                                    const unsigned short* __restrict__ kh,
                                                    const unsigned short* __restrict__ pvh,
                                                    unsigned short* __restrict__ catp) {
  int m0 = blockIdx.x * 64;
  int n = blockIdx.y, sc = blockIdx.z;
  int t = threadIdx.x, lane = t & 63, wv = t >> 6;
  int wc = (wv >> 1) * 64;      // c base (0/64)
  int wm2 = (wv & 1) * 32;      // m base within block tile (0/32)
  int r15 = lane & 15, kg = lane >> 4;
  int kq = kg ^ ((r15 >> 1) & 3);

  const unsigned short* qb  = qh + ((size_t)(sc * 16 + n) * 1024 + m0 + wv * 16) * 16;
  const unsigned short* kb  = kh + ((size_t)(sc * 16 + n) * 1024) * 16;
  const unsigned short* pvb = pvh + (size_t)n * 128 * 1024;

  __shared__ short PVs[2 * 128 * 32];
  __shared__ _Float16 Us[64 * 72];
  __shared__ float rsum[64];

  f16x8 zf = {0, 0, 0, 0, 0, 0, 0, 0};
  f16x8 qa = (kg < 2) ? *(const f16x8*)(qb + r15 * 16 + kg * 8) : zf;

  int prow = t >> 2;
  int aq = (t & 3) ^ ((prow >> 1) & 3);
  const unsigned short* Pb0 = pvb + (size_t)prow * 1024 + aq * 8;
  const unsigned short* Pb1 = pvb + (size_t)(prow + 64) * 1024 + aq * 8;
  char* ldsPV = (char*)PVs;
  int wvoff = wv * 1024;

  f32x4 acc[4][2];
#pragma unroll
  for (int i = 0; i < 4; ++i)
#pragma unroll
    for (int j = 0; j < 2; ++j) acc[i][j] = (f32x4){0.f, 0.f, 0.f, 0.f};
  float rs[4] = {0.f, 0.f, 0.f, 0.f};

  for (int it = 0; it < 16; ++it) {
    int l0 = it * 64;
    __syncthreads();
    gload_lds16(Pb0 + l0,      ldsPV + wvoff);
    gload_lds16(Pb1 + l0,      ldsPV + 4096 + wvoff);
    gload_lds16(Pb0 + l0 + 32, ldsPV + 8192 + wvoff);
    gload_lds16(Pb1 + l0 + 32, ldsPV + 12288 + wvoff);

    f32x4 sacc[4];
#pragma unroll
    for (int lt = 0; lt < 4; ++lt) {
      f16x8 kbf = (kg < 2)
        ? *(const f16x8*)(kb + (size_t)(l0 + lt * 16 + r15) * 16 + kg * 8) : zf;
      sacc[lt] = __builtin_amdgcn_mfma_f32_16x16x32_f16(qa, kbf, (f32x4){0.f,0.f,0.f,0.f}, 0, 0, 0);
    }
#pragma unroll
    for (int lt = 0; lt < 4; ++lt)
#pragma unroll
      for (int r = 0; r < 4; ++r) {
        float e = __expf(sacc[lt][r]);
        Us[(wv * 16 + kg * 4 + r) * 72 + lt * 16 + r15] = (_Float16)e;
        rs[r] += e;
      }
    __syncthreads();

#pragma unroll
    for (int ks = 0; ks < 2; ++ks) {
      f16x8 bfr[2];
#pragma unroll
      for (int nt = 0; nt < 2; ++nt)
        bfr[nt] = *(const f16x8*)&Us[(wm2 + nt * 16 + r15) * 72 + ks * 32 + kg * 8];
#pragma unroll
      for (int ct = 0; ct < 4; ++ct) {
        f16x8 af = *(const f16x8*)&PVs[ks * 4096 + (wc + ct * 16 + r15) * 32 + kq * 8];
#pragma unroll
        for (int nt = 0; nt < 2; ++nt)
          acc[ct][nt] = __builtin_amdgcn_mfma_f32_16x16x32_f16(af, bfr[nt], acc[ct][nt], 0, 0, 0);
      }
    }
  }

#pragma unroll
  for (int r = 0; r < 4; ++r) {
    rs[r] += __shfl_xor(rs[r], 1);
    rs[r] += __shfl_xor(rs[r], 2);
    rs[r] += __shfl_xor(rs[r], 4);
    rs[r] += __shfl_xor(rs[r], 8);
  }
  if (r15 == 0) {
#pragma unroll
    for (int r = 0; r < 4; ++r) rsum[wv * 16 + kg * 4 + r] = rs[r];
  }
  __syncthreads();

#pragma unroll
  for (int nt = 0; nt < 2; ++nt) {
    float inv = 1.f / rsum[wm2 + nt * 16 + r15];
    int pix = m0 + wm2 + nt * 16 + r15;
    unsigned short* ob = catp + ((size_t)n * 1156 + ((pix >> 5) + 1) * 34 + (pix & 31) + 1) * 256
                       + sc * 128 + wc + kg * 4;
#pragma unroll
    for (int ct = 0; ct < 4; ++ct) {
      ushort4 o = make_ushort4(f2bf(acc[ct][nt][0] * inv), f2bf(acc[ct][nt][1] * inv),
                               f2bf(acc[ct][nt][2] * inv), f2bf(acc[ct][nt][3] * inv));
      *(ushort4*)(ob + ct * 16) = o;
    }
  }
}

// ---------------- fusion conv as implicit GEMM (bf16 MFMA, K=2304) ----------------
// mean-channel contribution added from cor[n][oc][3x3] in the epilogue.
__global__ __launch_bounds__(256) void convmm_kernel(const unsigned short* __restrict__ Aw,
                                                     const unsigned short* __restrict__ catp,
                                                     const float* __restrict__ cor,
                                                     float* __restrict__ y) {
  int ntile = blockIdx.x;
  int n = ntile >> 3, y0 = (ntile & 7) * 4;
  int m0 = blockIdx.y * 128;
  int t = threadIdx.x;
  int lane = t & 63, wv = t >> 6;
  int wm = (wv & 1) * 64, wn = (wv >> 1) * 64;

  __shared__ short Asm[128 * 32];
  __shared__ short Bsm[128 * 32];

  int idx0 = t, idx1 = t + 256;
  int ar0 = idx0 >> 2, aq0 = (idx0 & 3) ^ ((ar0 >> 1) & 3);
  int ar1 = idx1 >> 2, aq1 = (idx1 & 3) ^ ((ar1 >> 1) & 3);
  size_t abase0 = (size_t)(m0 + ar0) * 2304 + aq0 * 8;
  size_t abase1 = (size_t)(m0 + ar1) * 2304 + aq1 * 8;
  size_t bbase0 = ((size_t)n * 1156 + (size_t)(y0 + (ar0 >> 5)) * 34 + (ar0 & 31)) * 256 + aq0 * 8;
  size_t bbase1 = ((size_t)n * 1156 + (size_t)(y0 + (ar1 >> 5)) * 34 + (ar1 & 31)) * 256 + aq1 * 8;
  char* ldsA = (char*)Asm;
  char* ldsB = (char*)Bsm;
  int wvoff = wv * 1024;

  int r15 = lane & 15, kg = lane >> 4;
  int kq = kg ^ ((r15 >> 1) & 3);

  f32x4 acc[4][4];
#pragma unroll
  for (int i = 0; i < 4; ++i)
#pragma unroll
    for (int j = 0; j < 4; ++j) acc[i][j] = (f32x4){0.f, 0.f, 0.f, 0.f};

  for (int seg = 0; seg < 9; ++seg) {
    size_t boffseg = (size_t)((seg / 3) * 34 + (seg % 3)) * 256;
    size_t akkseg = (size_t)seg * 256;
    for (int icc = 0; icc < 8; ++icc) {
      size_t akk = akkseg + icc * 32;
      size_t boff = boffseg + icc * 32;
      __syncthreads();
      gload_lds16(Aw + abase0 + akk,   ldsA + wvoff);
      gload_lds16(Aw + abase1 + akk,   ldsA + 4096 + wvoff);
      gload_lds16(catp + bbase0 + boff, ldsB + wvoff);
      gload_lds16(catp + bbase1 + boff, ldsB + 4096 + wvoff);
      __syncthreads();
      bf16x8 af[4], bf[4];
#pragma unroll
      for (int mt = 0; mt < 4; ++mt)
        af[mt] = *(const bf16x8*)&Asm[(wm + mt * 16 + r15) * 32 + kq * 8];
#pragma unroll
      for (int nt = 0; nt < 4; ++nt)
        bf[nt] = *(const bf16x8*)&Bsm[(wn + nt * 16 + r15) * 32 + kq * 8];
#pragma unroll
      for (int mt = 0; mt < 4; ++mt)
#pragma unroll
        for (int nt = 0; nt < 4; ++nt)
          acc[mt][nt] = __builtin_amdgcn_mfma_f32_16x16x32_bf16(af[mt], bf[nt], acc[mt][nt], 0, 0, 0);
    }
  }

  int pixbase = (ntile & 7) * 128 + wn + (lane & 15);
  int ocbase = m0 + wm + (lane >> 4) * 4;
#pragma unroll
  for (int mt = 0; mt < 4; ++mt)
#pragma unroll
    for (int nt = 0; nt < 4; ++nt) {
      int oc = ocbase + mt * 16;
      int pix = pixbase + nt * 16;
      int py = pix >> 5, px = pix & 31;
      int yc = (py == 0) ? 0 : ((py == 31) ? 2 : 1);
      int xc = (px == 0) ? 0 : ((px == 31) ? 2 : 1);
      const float* cp = cor + ((size_t)n * 512 + oc) * 9 + yc * 3 + xc;
      float* yp = y + ((size_t)n * 512 + oc) * 1024 + pix;
#pragma unroll
      for (int r = 0; r < 4; ++r) yp[(size_t)r * 1024] = acc[mt][nt][r] + cp[(size_t)r * 9];
    }
}

// ---------------- BN batch stats per channel ----------------
__global__ __launch_bounds__(256) void bnstat_kernel(const float* __restrict__ y,
                                                     const float* __restrict__ bn_scale,
                                                     const float* __restrict__ bn_bias,
                                                     float* __restrict__ stats) {
  int oc = blockIdx.x, t = threadIdx.x;
  float s = 0.f, ss = 0.f;
  for (int n = 0; n < 16; ++n) {
    float4 v = ((const float4*)(y + ((size_t)n * 512 + oc) * 1024))[t];
    s  += v.x + v.y + v.z + v.w;
    ss += v.x * v.x + v.y * v.y + v.z * v.z + v.w * v.w;
  }
  for (int o = 32; o > 0; o >>= 1) {
    s  += __shfl_down(s, o);
    ss += __shfl_down(ss, o);
  }
  __shared__ float rs[4], rss[4];
  if ((t & 63) == 0) { rs[t >> 6] = s; rss[t >> 6] = ss; }
  __syncthreads();
  if (t == 0) {
    float S = rs[0] + rs[1] + rs[2] + rs[3];
    float SS = rss[0] + rss[1] + rss[2] + rss[3];
    float mean = S * (1.f / 16384.f);
    float var = SS * (1.f / 16384.f) - mean * mean;
    float se = bn_scale[oc] / sqrtf(var + 1e-5f);
    stats[oc * 2] = se;
    stats[oc * 2 + 1] = bn_bias[oc] - mean * se;
  }
}

// ---------------- normalize + relu + gamma*y + x ----------------
__global__ __launch_bounds__(256) void final_kernel(const float* __restrict__ y,
                                                    const float* __restrict__ x,
                                                    const float* __restrict__ stats,
                                                    const float* __restrict__ gamma,
                                                    float* __restrict__ outp) {
  int b = blockIdx.x;
  int c = b & 511;
  int t = threadIdx.x;
  float se = stats[c * 2], sh = stats[c * 2 + 1], g = gamma[0];
  float4 yv = ((const float4*)(y + (size_t)b * 1024))[t];
  float4 xv = ((const float4*)(x + (size_t)b * 1024))[t];
  float4 o;
  o.x = g * fmaxf(yv.x * se + sh, 0.f) + xv.x;
  o.y = g * fmaxf(yv.y * se + sh, 0.f) + xv.y;
  o.z = g * fmaxf(yv.z * se + sh, 0.f) + xv.z;
  o.w = g * fmaxf(yv.w * se + sh, 0.f) + xv.w;
  ((float4*)(outp + (size_t)b * 1024))[t] = o;
}

extern "C" void kernel_launch(void* const* d_in, const int* in_sizes, int n_in,
                              void* d_out, int out_size, void* d_ws, size_t ws_size,
                              hipStream_t stream) {
  const float* x        = (const float*)d_in[0];
  const float* rce_w    = (const float*)d_in[1];
  const float* rce_b    = (const float*)d_in[2];
  const float* q_w      = (const float*)d_in[3];
  const float* q_b      = (const float*)d_in[4];
  const float* k_w      = (const float*)d_in[5];
  const float* k_b      = (const float*)d_in[6];
  const float* value_w  = (const float*)d_in[7];
  const float* value_b  = (const float*)d_in[8];
  const float* fw       = (const float*)d_in[9];
  const float* bn_scale = (const float*)d_in[10];
  const float* bn_bias  = (const float*)d_in[11];
  const float* gamma    = (const float*)d_in[12];

  float* ws    = (float*)d_ws;
  float* cor   = ws + OFF_COR;
  unsigned short* pvh = (unsigned short*)(ws + OFF_PVH);
  float* ybuf  = ws + OFF_Y;
  unsigned short* xTbuf = (unsigned short*)(ws + OFF_Y);  // union: dead before convmm
  unsigned short* catp = (unsigned short*)(ws + OFF_CATP);
  unsigned short* qh   = (unsigned short*)(ws + OFF_QH);
  unsigned short* kh   = (unsigned short*)(ws + OFF_KH);
  float* pool  = ws + OFF_POOL;
  float* feat  = ws + OFF_FEAT;
  unsigned short* Aw = (unsigned short*)(ws + OFF_AW);
  float* means = ws + OFF_MEANS;
  float* stats = ws + OFF_STAT;
  unsigned short* vwh = (unsigned short*)(ws + OFF_VWH);
  float* outp  = (float*)d_out;

  hipLaunchKernelGGL(pool_kernel,    dim3(8192),       dim3(256), 0, stream, x, pool);
  hipLaunchKernelGGL(feat_kernel,    dim3(128, 16),    dim3(64),  0, stream, pool, rce_w, rce_b, feat);
  hipLaunchKernelGGL(qk2_kernel,     dim3(16),         dim3(256), 0, stream, feat, q_w, q_b, k_w, k_b, qh, kh);
  hipLaunchKernelGGL(xcast_kernel,   dim3(16, 8, 16),  dim3(256), 0, stream, x, xTbuf);
  hipLaunchKernelGGL(vwcast_kernel,  dim3(256),        dim3(256), 0, stream, value_w, vwh);
  hipLaunchKernelGGL(pvmm2_kernel,   dim3(16, 16),     dim3(256), 0, stream, vwh, xTbuf, value_b, pvh);
  hipLaunchKernelGGL(mean_kernel,    dim3(128, 16),    dim3(256), 0, stream, pvh, means);
  hipLaunchKernelGGL(basecor_kernel, dim3(512, 16),    dim3(64),  0, stream, means, fw, cor);
  hipLaunchKernelGGL(fillcat_kernel, dim3(2112),       dim3(128), 0, stream, catp);
  hipLaunchKernelGGL(wcast_kernel,   dim3(512),        dim3(256), 0, stream, fw, Aw);
  hipLaunchKernelGGL(fattn_kernel,   dim3(16, 16, 2),  dim3(256), 0, stream, qh, kh, pvh, catp);
  hipLaunchKernelGGL(convmm_kernel,  dim3(128, 4),     dim3(256), 0, stream, Aw, catp, cor, ybuf);
  hipLaunchKernelGGL(bnstat_kernel,  dim3(512),        dim3(256), 0, stream, ybuf, bn_scale, bn_bias, stats);
  hipLaunchKernelGGL(final_kernel,   dim3(8192),       dim3(256), 0, stream, ybuf, x, stats, gamma, outp);
}